// Round 15
// baseline (301.309 us; speedup 1.0000x reference)
//
#include <hip/hip_runtime.h>

// Problem constants (fixed by setup_inputs)
#define B_  2
#define CK_ 64
#define CV_ 512
#define H_  48
#define W_  48
#define M_  18432   // T*H*W
#define N_  2304    // H*W

#define SSPLIT 8
#define MSEG   (M_ / SSPLIT)   // 2304
#define VSTRIDE16 (CV_ * 16)   // elems per m16 block in vt = 8192

typedef __bf16 bf16x8 __attribute__((ext_vector_type(8)));
typedef float  f32x4  __attribute__((ext_vector_type(4)));
typedef float  f32x16 __attribute__((ext_vector_type(16)));
typedef unsigned int u32x4 __attribute__((ext_vector_type(4)));

// logit = (2*ab - |k|^2)/sqrt(64); exp2 domain. Q pre-scaled by C2Q,
// ksq pre-scaled by C_KSQ, stored as bf16 hi+lo pair.
#define C2Q   0.36067376f
#define C_KSQ 0.18033688f

__device__ inline f32x16 mfma32(bf16x8 a, bf16x8 b, f32x16 c) {
    return __builtin_amdgcn_mfma_f32_32x32x16_bf16(a, b, c, 0, 0, 0);
}

__device__ inline unsigned pack_bf16(float lo, float hi) {
    union { __bf16 h; unsigned short u; } a, b;
    a.h = (__bf16)lo; b.h = (__bf16)hi;
    return ((unsigned)b.u << 16) | a.u;
}

// async global->LDS, 16B per lane; LDS dest = uniform base + lane*16 (HW).
__device__ __forceinline__ void gload_lds16(const __bf16* g, __bf16* l) {
    __builtin_amdgcn_global_load_lds(
        (const __attribute__((address_space(1))) void*)g,
        (__attribute__((address_space(3))) void*)l,
        16, 0, 0);
}

// ---------------------------------------------------------------------------
// prep_k: ktile[b][mt][ks][h][l][8] : elem = K[b][m=32mt+l][k=16ks+8h+i]
// (QK A-frag load = contiguous 1KB wave-load). ksq2 = packed bf16 {hi,lo}.
// ---------------------------------------------------------------------------
__global__ __launch_bounds__(256) void prep_k(const float* __restrict__ mk,
                                              __bf16* __restrict__ ktile,
                                              unsigned* __restrict__ ksq2) {
    const int idx = blockIdx.x * 256 + threadIdx.x;   // B*M threads
    const int b = idx / M_, m = idx % M_;
    const float* src = mk + (size_t)b * CK_ * M_ + m;
    const int mt = m >> 5, l = m & 31;
    __bf16* dstb = ktile + (size_t)b * M_ * 64 + (size_t)mt * 2048 + l * 8;
    float s = 0.f;
#pragma unroll
    for (int j = 0; j < 8; ++j) {          // octet j: ks = j>>1, h = j&1
        bf16x8 o;
#pragma unroll
        for (int i = 0; i < 8; ++i) {
            float v = src[(size_t)(8 * j + i) * M_];
            s += v * v;
            o[i] = (__bf16)v;
        }
        *(bf16x8*)(dstb + (size_t)j * 256) = o;
    }
    const float tot = s * C_KSQ;
    const float hi = (float)(__bf16)tot;
    const float lo = tot - hi;
    ksq2[idx] = pack_bf16(hi, lo);
}

// ---------------------------------------------------------------------------
// prep_v: vt[b][m16][c][16] : elem = V[b][c][m=16*m16+i].
// ---------------------------------------------------------------------------
__global__ __launch_bounds__(256) void prep_v(const float* __restrict__ mv,
                                              __bf16* __restrict__ vt) {
    const int idx = blockIdx.x * 256 + threadIdx.x;   // B*1152*CV threads
    const int c   = idx % CV_;
    const int r   = idx / CV_;
    const int m16 = r % (M_ / 16);
    const int b   = r / (M_ / 16);
    const float4* s4 = (const float4*)(mv + ((size_t)b * CV_ + c) * M_ + m16 * 16);
    const float4 a0 = s4[0], a1 = s4[1], a2 = s4[2], a3 = s4[3];
    bf16x8 o0, o1;
    o0[0]=(__bf16)a0.x; o0[1]=(__bf16)a0.y; o0[2]=(__bf16)a0.z; o0[3]=(__bf16)a0.w;
    o0[4]=(__bf16)a1.x; o0[5]=(__bf16)a1.y; o0[6]=(__bf16)a1.z; o0[7]=(__bf16)a1.w;
    o1[0]=(__bf16)a2.x; o1[1]=(__bf16)a2.y; o1[2]=(__bf16)a2.z; o1[3]=(__bf16)a2.w;
    o1[4]=(__bf16)a3.x; o1[5]=(__bf16)a3.y; o1[6]=(__bf16)a3.z; o1[7]=(__bf16)a3.w;
    __bf16* dst = vt + ((size_t)r * CV_ + c) * 16;
    *(bf16x8*)dst = o0;
    *(bf16x8*)(dst + 8) = o1;
}

// ---------------------------------------------------------------------------
// flash13: duty-rotation producer/consumer flash.
// Block = 32 queries x ALL 512 channels x M/8 segment (grid 1152, 4 waves).
// Per strip s: ONE duty wave (w == (s+1)&3) computes QK(s+1)+exp+pack+
// permlane and publishes the 2KB P B-frag to LDS (double-buffered); ALL
// waves run PV(s) (8 MFMA over their 128 channels) with the shared P.
// QK/exp/pack now computed ONCE per (n-tile, strip) -- was 2x (cs2 split).
// K prefetched 4 bodies ahead (per-wave duty cadence). V staged in LDS
// (r14's verified conflict-free pre-swizzled linear layout), 2x32KB.
// Math/fragment layouts identical to rounds 5-14 (verified absmax 0.0156).
// ---------------------------------------------------------------------------

// stage next strip's V (32KB = 32 x 1KB pieces, 8 per wave) into LDS
#define STAGEV(vnxt) do {                                                     \
    _Pragma("unroll")                                                         \
    for (int i = 0; i < 8; ++i) {                                             \
        const int j = i * 4 + w;                                              \
        const int chunk = j >> 4, off = j & 15;                               \
        gload_lds16(vps + chunk * VSTRIDE16 + off * 512 + soff,               \
                    (vnxt) + chunk * 8192 + off * 512);                       \
    }                                                                         \
    vps += 2 * VSTRIDE16;                                                     \
} while (0)

// duty work: QK for strip (scur+1) from kC/kqC; publish P B-frags to pdst.
#define DUTY(pdst) do {                                                       \
    u32x4 _a4u = { h ? 0u : kqC, 0u, 0u, 0u };                                \
    const bf16x8 _af4 = __builtin_bit_cast(bf16x8, _a4u);                     \
    __builtin_amdgcn_s_setprio(1);                                            \
    f32x16 _d = mfma32(_af4, bneg, fzero);                                    \
    _d = mfma32(kC0, qf[0], _d);                                              \
    _d = mfma32(kC1, qf[1], _d);                                              \
    _d = mfma32(kC2, qf[2], _d);                                              \
    _d = mfma32(kC3, qf[3], _d);                                              \
    __builtin_amdgcn_s_setprio(0);                                            \
    unsigned _wpk[8];                                                         \
    _Pragma("unroll")                                                         \
    for (int j = 0; j < 8; ++j) {                                             \
        const float _pa = __builtin_amdgcn_exp2f(_d[2*j]);                    \
        const float _pc = __builtin_amdgcn_exp2f(_d[2*j+1]);                  \
        den[j & 3] += _pa + _pc;                                              \
        _wpk[j] = pack_bf16(_pa, _pc);                                        \
    }                                                                         \
    bf16x8 _pb0h, _pb1h;                                                      \
    {                                                                         \
        unsigned _a0 = _wpk[0], _b0 = _wpk[2];                                \
        unsigned _a1 = _wpk[1], _b1 = _wpk[3];                                \
        asm volatile("v_permlane32_swap_b32 %0, %1" : "+v"(_a0), "+v"(_b0));  \
        asm volatile("v_permlane32_swap_b32 %0, %1" : "+v"(_a1), "+v"(_b1));  \
        u32x4 _pu = {_a0, _a1, _b0, _b1};                                     \
        _pb0h = __builtin_bit_cast(bf16x8, _pu);                              \
    }                                                                         \
    {                                                                         \
        unsigned _a0 = _wpk[4], _b0 = _wpk[6];                                \
        unsigned _a1 = _wpk[5], _b1 = _wpk[7];                                \
        asm volatile("v_permlane32_swap_b32 %0, %1" : "+v"(_a0), "+v"(_b0));  \
        asm volatile("v_permlane32_swap_b32 %0, %1" : "+v"(_a1), "+v"(_b1));  \
        u32x4 _pu = {_a0, _a1, _b0, _b1};                                     \
        _pb1h = __builtin_bit_cast(bf16x8, _pu);                              \
    }                                                                         \
    *(bf16x8*)((pdst) + lane * 8)       = _pb0h;                              \
    *(bf16x8*)((pdst) + 512 + lane * 8) = _pb1h;                              \
} while (0)

#define LOADK_AT(t) do {                                                      \
    const __bf16* _kpt = kp + (size_t)(t) * 2048;                             \
    kC0 = *(const bf16x8*)(_kpt + koff);                                      \
    kC1 = *(const bf16x8*)(_kpt + koff + 512);                                \
    kC2 = *(const bf16x8*)(_kpt + koff + 1024);                               \
    kC3 = *(const bf16x8*)(_kpt + koff + 1536);                               \
    kqC = kqp[(t) * 32 + l31];                                                \
} while (0)

// body for strip scur: V(scur)/P(scur) ready in vcur/pcur (fenced by the top
// barrier); stage V(scur+1)->vnxt; duty wave publishes P(scur+1)->pnxt and
// prefetches K(scur+5); all waves PV(scur).
#define BODY(vcur, vnxt, pcur, pnxt, STAGE, DOQK) do {                        \
    __syncthreads();                                                          \
    if (STAGE) STAGEV(vnxt);                                                  \
    if (DOQK && w == ((scur + 1) & 3)) {                                      \
        DUTY(pnxt);                                                           \
        if (scur <= 66) LOADK_AT(scur + 5);                                   \
    }                                                                         \
    const bf16x8 _pb0 = *(const bf16x8*)((pcur) + vloff);                     \
    const bf16x8 _pb1 = *(const bf16x8*)((pcur) + 512 + vloff);               \
    const bf16x8 _va0 = *(const bf16x8*)((vcur) + w2048 + vloff);             \
    const bf16x8 _va1 = *(const bf16x8*)((vcur) + w2048 + 512 + vloff);       \
    const bf16x8 _va2 = *(const bf16x8*)((vcur) + w2048 + 1024 + vloff);      \
    const bf16x8 _va3 = *(const bf16x8*)((vcur) + w2048 + 1536 + vloff);      \
    const bf16x8 _vb0 = *(const bf16x8*)((vcur) + 8192 + w2048 + vloff);      \
    const bf16x8 _vb1 = *(const bf16x8*)((vcur) + 8192 + w2048 + 512 + vloff);\
    const bf16x8 _vb2 = *(const bf16x8*)((vcur) + 8192 + w2048 + 1024 + vloff);\
    const bf16x8 _vb3 = *(const bf16x8*)((vcur) + 8192 + w2048 + 1536 + vloff);\
    __builtin_amdgcn_s_setprio(1);                                            \
    acc[0] = mfma32(_va0, _pb0, acc[0]);                                      \
    acc[1] = mfma32(_va1, _pb0, acc[1]);                                      \
    acc[2] = mfma32(_va2, _pb0, acc[2]);                                      \
    acc[3] = mfma32(_va3, _pb0, acc[3]);                                      \
    acc[0] = mfma32(_vb0, _pb1, acc[0]);                                      \
    acc[1] = mfma32(_vb1, _pb1, acc[1]);                                      \
    acc[2] = mfma32(_vb2, _pb1, acc[2]);                                      \
    acc[3] = mfma32(_vb3, _pb1, acc[3]);                                      \
    __builtin_amdgcn_s_setprio(0);                                            \
    ++scur;                                                                   \
} while (0)

__global__ __launch_bounds__(256, 2) void flash13_kernel(const __bf16* __restrict__ ktile,
                                                         const float* __restrict__ qk,
                                                         const __bf16* __restrict__ vt,
                                                         const unsigned* __restrict__ ksq2,
                                                         __bf16* __restrict__ partO,
                                                         float* __restrict__ partD) {
    const int tid = threadIdx.x;
    const int w = tid >> 6, lane = tid & 63;
    const int l31 = lane & 31, h = lane >> 5;

    // XCD-chunked decomposition: 16 groups (s,b) x 72 n-tile blocks; each
    // group's 72 blocks land on one XCD -> shared K/V stream in its L2.
    const int bid = blockIdx.x;            // 0..1151
    const int xcd = bid & 7;
    const int ixc = bid >> 3;              // 0..143
    const int grp = ixc / 72;              // 0..1
    const int nt  = ixc % 72;
    const int G   = xcd * 2 + grp;         // 0..15
    const int s   = G & 7, b = G >> 3;

    const int n0 = nt * 32;
    const int m_base = s * MSEG;

    // lane-invariant offsets (elements), computed ONCE
    const int koff  = (h * 32 + l31) * 8;
    const int vloff = lane * 8;                            // linear LDS reads
    const int soff  = (lane & 31) * 16 + (lane >> 5) * 8;  // pre-swizzled src
    const int w2048 = w * 2048;                            // wave channel window

    // shared: V strips (fragment-ordered), P B-frags, denominator reduce
    __shared__ __align__(16) __bf16 Vlds[2][16384];   // 2 x 32KB
    __shared__ __align__(16) __bf16 Plds[2][1024];    // 2 x 2KB
    __shared__ float dred[4][32];

    // Q' B-frags: col = n0+l31, k = 16ks+8h+i, scaled by C2Q
    const float* qkb = qk + (size_t)b * CK_ * N_;
    bf16x8 qf[4];
#pragma unroll
    for (int ks = 0; ks < 4; ++ks)
#pragma unroll
      for (int i = 0; i < 8; ++i)
        qf[ks][i] = (__bf16)(qkb[(size_t)(16*ks + 8*h + i) * N_ + (n0 + l31)] * C2Q);

    // constant B-frag: -1.0bf16 at k slots {0,1}
    const u32x4 bneg_u = {0xBF80BF80u, 0u, 0u, 0u};
    const bf16x8 bneg = __builtin_bit_cast(bf16x8, bneg_u);

    // persistent zero accumulator (C operand of the first QK MFMA)
    f32x16 fzero;
#pragma unroll
    for (int r = 0; r < 16; ++r) fzero[r] = 0.f;

    // wave-uniform stream pointers
    const __bf16*   kp  = ktile + (size_t)b * M_ * 64 + (size_t)m_base * 64;
    const unsigned* kqp = ksq2  + (size_t)b * M_ + m_base;
    const __bf16*   vps = vt    + (size_t)b * M_ * CV_ + (size_t)m_base * CV_;

    f32x16 acc[4];
#pragma unroll
    for (int ct = 0; ct < 4; ++ct)
#pragma unroll
      for (int r = 0; r < 16; ++r) acc[ct][r] = 0.f;
    float den[4] = {0.f, 0.f, 0.f, 0.f};

    bf16x8 kC0, kC1, kC2, kC3;
    unsigned kqC;
    int scur = 0;

    // prologue: stage V(0); wave w loads K(first duty strip); wave 0
    // computes QK(0) -> P(0) in Plds[0], then prefetches K(4).
    STAGEV(&Vlds[0][0]);
    {
        const int t0 = (w == 0) ? 0 : w;
        LOADK_AT(t0);
    }
    if (w == 0) {
        DUTY(&Plds[0][0]);
        LOADK_AT(4);
    }

    for (int it = 0; it < 35; ++it) {                 // strips 0..69
        BODY(&Vlds[0][0], &Vlds[1][0], &Plds[0][0], &Plds[1][0], 1, 1);
        BODY(&Vlds[1][0], &Vlds[0][0], &Plds[1][0], &Plds[0][0], 1, 1);
    }
    // strip 70: stages V(71), publishes P(71)
    BODY(&Vlds[0][0], &Vlds[1][0], &Plds[0][0], &Plds[1][0], 1, 1);
    // strip 71: nothing prefetched
    BODY(&Vlds[1][0], &Vlds[0][0], &Plds[1][0], &Plds[0][0], 0, 0);

    // denominator: per-wave duty-strip sums -> cross-wave reduce -> partD
    float dsum = (den[0] + den[1]) + (den[2] + den[3]);
    dsum += __shfl_xor(dsum, 32);
    __syncthreads();
    if (lane < 32) dred[w][l31] = dsum;
    __syncthreads();
    if (tid < 32) {
        const float tot = (dred[0][tid] + dred[1][tid]) + (dred[2][tid] + dred[3][tid]);
        partD[(size_t)(s * B_ + b) * N_ + n0 + tid] = tot;
    }

    // unnormalized partial O in bf16: c = 128w + 32ct + (r&3)+8*(r>>2)+4h
    __bf16* po = partO + (((size_t)(s * B_ + b) * CV_ + 128 * w) * N_) + n0 + l31;
#pragma unroll
    for (int ct = 0; ct < 4; ++ct)
#pragma unroll
      for (int r = 0; r < 16; ++r) {
        const int crow = 32*ct + (r & 3) + 8*(r >> 2) + 4*h;
        po[(size_t)crow * N_] = (__bf16)acc[ct][r];
      }
}

// ---------------------------------------------------------------------------
// reduce: mem[b][c][n] = sum_s partO / sum_s partD  -> d_out channels 0..511
// ---------------------------------------------------------------------------
__global__ __launch_bounds__(256) void reduce_kernel(const __bf16* __restrict__ partO,
                                                     const float* __restrict__ partD,
                                                     float* __restrict__ out) {
    const int idx = blockIdx.x * 256 + threadIdx.x;   // B*CV*(N/8) threads
    const int n8 = idx % (N_ / 8);
    const int c  = (idx / (N_ / 8)) % CV_;
    const int b  = idx / ((N_ / 8) * CV_);
    float o[8] = {0,0,0,0,0,0,0,0};
    float dd[8] = {0,0,0,0,0,0,0,0};
#pragma unroll
    for (int s = 0; s < SSPLIT; ++s) {
        const bf16x8 ov = *(const bf16x8*)(partO + (((size_t)(s*B_+b)*CV_ + c) * N_) + n8*8);
        const float4 d0 = *(const float4*)(partD + (size_t)(s*B_+b)*N_ + n8*8);
        const float4 d1 = *(const float4*)(partD + (size_t)(s*B_+b)*N_ + n8*8 + 4);
#pragma unroll
        for (int j = 0; j < 8; ++j) o[j] += (float)ov[j];
        dd[0]+=d0.x; dd[1]+=d0.y; dd[2]+=d0.z; dd[3]+=d0.w;
        dd[4]+=d1.x; dd[5]+=d1.y; dd[6]+=d1.z; dd[7]+=d1.w;
    }
    float* op = out + ((size_t)b * (2*CV_) + c) * N_ + n8*8;
#pragma unroll
    for (int j = 0; j < 8; ++j) op[j] = o[j] / dd[j];
}

// ---------------------------------------------------------------------------
// conv_r: R_j[cc][b][p] = sum_{c in chunk cc} in[c][p] * w[c][j]
// ---------------------------------------------------------------------------
__global__ __launch_bounds__(256) void conv_r_kernel(const float* __restrict__ outf,
                                                     const float* __restrict__ qv,
                                                     const float* __restrict__ mask,
                                                     const float* __restrict__ cw,
                                                     float* __restrict__ Rp) {
    const int p  = blockIdx.x * 256 + threadIdx.x;   // 0..N-1
    const int cc = blockIdx.y;                        // 0..8
    const int b  = blockIdx.z;
    float r[9] = {0,0,0,0,0,0,0,0,0};
    if (cc < 8) {
        const float* src = (cc < 4) ? outf + ((size_t)b * (2*CV_) + cc * 128) * N_
                                    : qv   + ((size_t)b * CV_ + (cc - 4) * 128) * N_;
        const float* wb = cw + (size_t)cc * 128 * 9;
        for (int c = 0; c < 128; ++c) {
            const float v = src[(size_t)c * N_ + p];
#pragma unroll
            for (int j = 0; j < 9; ++j) r[j] += v * wb[c * 9 + j];
        }
    } else {
        const float v = mask[(size_t)b * N_ + p];
#pragma unroll
        for (int j = 0; j < 9; ++j) r[j] = v * cw[1024 * 9 + j];
    }
#pragma unroll
    for (int j = 0; j < 9; ++j)
        Rp[(((size_t)cc * 9 + j) * B_ + b) * N_ + p] = r[j];
}

// ---------------------------------------------------------------------------
// gate: gate[b][p] = sigmoid( sum_j sum_cc Rp[cc][j][b][neighbor_j(p)] + bias )
// ---------------------------------------------------------------------------
__global__ __launch_bounds__(256) void gate_kernel(const float* __restrict__ Rp,
                                                   const float* __restrict__ cbias,
                                                   float* __restrict__ gate_ws) {
    const int p = blockIdx.x * 256 + threadIdx.x;    // 0..N-1
    const int b = blockIdx.y;
    const int y = p / W_, x = p % W_;
    float sum = cbias[0];
#pragma unroll
    for (int dy = -1; dy <= 1; ++dy) {
        const int yy = y + dy;
        if (yy < 0 || yy >= H_) continue;
#pragma unroll
        for (int dx = -1; dx <= 1; ++dx) {
            const int xx = x + dx;
            if (xx < 0 || xx >= W_) continue;
            const int j = (dy + 1) * 3 + (dx + 1);
            const int q = yy * W_ + xx;
#pragma unroll
            for (int cc = 0; cc < 9; ++cc)
                sum += Rp[(((size_t)cc * 9 + j) * B_ + b) * N_ + q];
        }
    }
    gate_ws[(size_t)b * N_ + p] = 1.f / (1.f + __builtin_amdgcn_exp2f(-sum * 1.44269504f));
}

// ---------------------------------------------------------------------------
// finalize: out[b][ch][n] = (ch<512 ? mem : qv) * gate[b][n]
// ---------------------------------------------------------------------------
__global__ __launch_bounds__(256) void finalize_kernel(const float* __restrict__ qv,
                                                       const float* __restrict__ gate_ws,
                                                       float* __restrict__ out) {
    const int idx = blockIdx.x * 256 + threadIdx.x;
    const int n4 = N_ / 4;
    const int pos4 = idx % n4;
    const int row  = idx / n4;
    const int b = row >> 10, ch = row & 1023;
    const float4 gv = *(const float4*)(gate_ws + (size_t)b * N_ + pos4 * 4);
    float* op = out + (size_t)row * N_ + pos4 * 4;
    float4 v;
    if (ch < CV_) v = *(const float4*)op;
    else          v = *(const float4*)(qv + ((size_t)b * CV_ + (ch - CV_)) * N_ + pos4 * 4);
    v.x *= gv.x; v.y *= gv.y; v.z *= gv.z; v.w *= gv.w;
    *(float4*)op = v;
}

// ===========================================================================
extern "C" void kernel_launch(void* const* d_in, const int* in_sizes, int n_in,
                              void* d_out, int out_size, void* d_ws, size_t ws_size,
                              hipStream_t stream) {
    (void)in_sizes; (void)n_in; (void)out_size; (void)ws_size;
    const float* mk    = (const float*)d_in[0];
    const float* qk    = (const float*)d_in[1];
    const float* mv    = (const float*)d_in[2];
    const float* qv    = (const float*)d_in[3];
    const float* mask  = (const float*)d_in[4];
    const float* cw    = (const float*)d_in[5];
    const float* cbias = (const float*)d_in[6];
    float* outf = (float*)d_out;

    // workspace layout (bytes) — total 80,529,408, byte-identical to rounds 3-14
    const size_t kbf_b   = (size_t)B_ * M_ * 64 * 2;             //  4,718,592 (ktile; reused as Rp)
    const size_t vbf_b   = (size_t)B_ * CV_ * M_ * 2;            // 37,748,736 (vt)
    const size_t ksq_b   = (size_t)B_ * M_ * 4;                  //    147,456 (packed u32 hi/lo)
    const size_t partO_b = (size_t)SSPLIT * B_ * CV_ * N_ * 2;   // 37,748,736 (bf16)
    const size_t partD_b = (size_t)SSPLIT * B_ * N_ * 4;         //    147,456

    char* pw = (char*)d_ws;
    __bf16* ktile = (__bf16*)pw;
    float*  Rp    = (float*)pw;            // overlays ktile (dead after flash13)
    pw += kbf_b;
    __bf16* vt    = (__bf16*)pw;           pw += vbf_b;
    unsigned* ksq2 = (unsigned*)pw;        pw += ksq_b;
    __bf16* partO = (__bf16*)pw;           pw += partO_b;
    float*  partD = (float*)pw;            pw += partD_b;
    float*  gate_ws = (float*)pw;

    prep_k<<<dim3(B_ * M_ / 256), 256, 0, stream>>>(mk, ktile, ksq2);
    prep_v<<<dim3((size_t)B_ * (M_ / 16) * CV_ / 256, 1, 1), 256, 0, stream>>>(mv, vt);
    flash13_kernel<<<dim3(1152), 256, 0, stream>>>(ktile, qk, vt, ksq2, partO, partD);
    reduce_kernel<<<dim3(B_ * CV_ * (N_ / 8) / 256), 256, 0, stream>>>(partO, partD, outf);
    conv_r_kernel<<<dim3(N_ / 256, 9, B_), 256, 0, stream>>>(outf, qv, mask, cw, Rp);
    gate_kernel<<<dim3(N_ / 256, B_), 256, 0, stream>>>(Rp, cbias, gate_ws);
    finalize_kernel<<<dim3((B_ * 2 * CV_ * N_ / 4) / 256), 256, 0, stream>>>(qv, gate_ws, outf);
}

// Round 16
// 249.200 us; speedup vs baseline: 1.2091x; 1.2091x over previous
//
#include <hip/hip_runtime.h>

// Problem constants (fixed by setup_inputs)
#define B_  2
#define CK_ 64
#define CV_ 512
#define H_  48
#define W_  48
#define M_  18432   // T*H*W
#define N_  2304    // H*W

#define SSPLIT 8
#define MSEG   (M_ / SSPLIT)   // 2304
#define VSTRIDE16 (CV_ * 16)   // elems per m16 block in vt = 8192

typedef __bf16 bf16x8 __attribute__((ext_vector_type(8)));
typedef float  f32x4  __attribute__((ext_vector_type(4)));
typedef float  f32x16 __attribute__((ext_vector_type(16)));
typedef unsigned int u32x4 __attribute__((ext_vector_type(4)));

// logit = (2*ab - |k|^2)/sqrt(64); exp2 domain. Q pre-scaled by C2Q,
// ksq pre-scaled by C_KSQ, stored as bf16 hi+lo pair.
#define C2Q   0.36067376f
#define C_KSQ 0.18033688f

__device__ inline f32x16 mfma32(bf16x8 a, bf16x8 b, f32x16 c) {
    return __builtin_amdgcn_mfma_f32_32x32x16_bf16(a, b, c, 0, 0, 0);
}

__device__ inline unsigned pack_bf16(float lo, float hi) {
    union { __bf16 h; unsigned short u; } a, b;
    a.h = (__bf16)lo; b.h = (__bf16)hi;
    return ((unsigned)b.u << 16) | a.u;
}

// async global->LDS, 16B per lane; LDS dest = uniform base + lane*16 (HW).
__device__ __forceinline__ void gload_lds16(const __bf16* g, __bf16* l) {
    __builtin_amdgcn_global_load_lds(
        (const __attribute__((address_space(1))) void*)g,
        (__attribute__((address_space(3))) void*)l,
        16, 0, 0);
}

// ---------------------------------------------------------------------------
// prep_k: ktile[b][mt][ks][h][l][8] : elem = K[b][m=32mt+l][k=16ks+8h+i]
// (QK A-frag load = contiguous 1KB wave-load). ksq2 = packed bf16 {hi,lo}.
// ---------------------------------------------------------------------------
__global__ __launch_bounds__(256) void prep_k(const float* __restrict__ mk,
                                              __bf16* __restrict__ ktile,
                                              unsigned* __restrict__ ksq2) {
    const int idx = blockIdx.x * 256 + threadIdx.x;   // B*M threads
    const int b = idx / M_, m = idx % M_;
    const float* src = mk + (size_t)b * CK_ * M_ + m;
    const int mt = m >> 5, l = m & 31;
    __bf16* dstb = ktile + (size_t)b * M_ * 64 + (size_t)mt * 2048 + l * 8;
    float s = 0.f;
#pragma unroll
    for (int j = 0; j < 8; ++j) {          // octet j: ks = j>>1, h = j&1
        bf16x8 o;
#pragma unroll
        for (int i = 0; i < 8; ++i) {
            float v = src[(size_t)(8 * j + i) * M_];
            s += v * v;
            o[i] = (__bf16)v;
        }
        *(bf16x8*)(dstb + (size_t)j * 256) = o;
    }
    const float tot = s * C_KSQ;
    const float hi = (float)(__bf16)tot;
    const float lo = tot - hi;
    ksq2[idx] = pack_bf16(hi, lo);
}

// ---------------------------------------------------------------------------
// prep_v: vt[b][m16][c][16] : elem = V[b][c][m=16*m16+i].
// ---------------------------------------------------------------------------
__global__ __launch_bounds__(256) void prep_v(const float* __restrict__ mv,
                                              __bf16* __restrict__ vt) {
    const int idx = blockIdx.x * 256 + threadIdx.x;   // B*1152*CV threads
    const int c   = idx % CV_;
    const int r   = idx / CV_;
    const int m16 = r % (M_ / 16);
    const int b   = r / (M_ / 16);
    const float4* s4 = (const float4*)(mv + ((size_t)b * CV_ + c) * M_ + m16 * 16);
    const float4 a0 = s4[0], a1 = s4[1], a2 = s4[2], a3 = s4[3];
    bf16x8 o0, o1;
    o0[0]=(__bf16)a0.x; o0[1]=(__bf16)a0.y; o0[2]=(__bf16)a0.z; o0[3]=(__bf16)a0.w;
    o0[4]=(__bf16)a1.x; o0[5]=(__bf16)a1.y; o0[6]=(__bf16)a1.z; o0[7]=(__bf16)a1.w;
    o1[0]=(__bf16)a2.x; o1[1]=(__bf16)a2.y; o1[2]=(__bf16)a2.z; o1[3]=(__bf16)a2.w;
    o1[4]=(__bf16)a3.x; o1[5]=(__bf16)a3.y; o1[6]=(__bf16)a3.z; o1[7]=(__bf16)a3.w;
    __bf16* dst = vt + ((size_t)r * CV_ + c) * 16;
    *(bf16x8*)dst = o0;
    *(bf16x8*)(dst + 8) = o1;
}

// ---------------------------------------------------------------------------
// flash14: round-14 flash12 (verified 161us) with TWO strips per barrier
// phase. V staged 32KB/phase into a 2x32KB LDS double buffer -> 36 barriers
// instead of 72; stage loads get a 2-strip flight; longer barrier-free
// regions let the 2 resident blocks/CU overlap phases. Registers, math,
// K cadence, fragment layouts identical to round 14 (absmax 0.0156).
// ---------------------------------------------------------------------------

#define LOADK(k0, k1, k2, k3, kq) do {                                        \
    k0 = *(const bf16x8*)(kp + koff);                                         \
    k1 = *(const bf16x8*)(kp + koff + 512);                                   \
    k2 = *(const bf16x8*)(kp + koff + 1024);                                  \
    k3 = *(const bf16x8*)(kp + koff + 1536);                                  \
    kq = kqp[l31];                                                            \
    kp += 2048; kqp += 32;                                                    \
} while (0)

// stage next PHASE's V (2 strips = 32KB = 32 x 1KB pieces, 8 per wave).
// Per-lane source permuted so linear LDS order == fragment-read order (r14).
#define STAGEV2(vnxt) do {                                                    \
    _Pragma("unroll")                                                         \
    for (int i = 0; i < 8; ++i) {                                             \
        const int j = i * 4 + w;                                              \
        const int chunk = j >> 3, off = j & 7;                                \
        gload_lds16(vps + chunk * VSTRIDE16 + cwoff + off * 512 + soff,       \
                    (vnxt) + chunk * 4096 + off * 512);                       \
    }                                                                         \
    vps += 4 * VSTRIDE16;                                                     \
} while (0)

// one strip body (no barrier/stage): V at vbase (8KB ks0 | 8KB ks1)
#define STRIPBODY(vbase, RELOADK) do {                                        \
    u32x4 _a4u = { h ? 0u : kqC, 0u, 0u, 0u };                                \
    const bf16x8 _af4 = __builtin_bit_cast(bf16x8, _a4u);                     \
    __builtin_amdgcn_s_setprio(1);                                            \
    f32x16 _d = mfma32(_af4, bneg, fzero);                                    \
    _d = mfma32(kC0, qf[0], _d);                                              \
    _d = mfma32(kC1, qf[1], _d);                                              \
    _d = mfma32(kC2, qf[2], _d);                                              \
    _d = mfma32(kC3, qf[3], _d);                                              \
    __builtin_amdgcn_s_setprio(0);                                            \
    if (RELOADK) LOADK(kC0, kC1, kC2, kC3, kqC);   /* K(s+1), regs dead */    \
    unsigned _wpk[8];                                                         \
    _Pragma("unroll")                                                         \
    for (int j = 0; j < 8; ++j) {                                             \
        const float _pa = __builtin_amdgcn_exp2f(_d[2*j]);                    \
        const float _pc = __builtin_amdgcn_exp2f(_d[2*j+1]);                  \
        den[j & 3] += _pa + _pc;                                              \
        _wpk[j] = pack_bf16(_pa, _pc);                                        \
    }                                                                         \
    bf16x8 _pb0, _pb1;                                                        \
    {                                                                         \
        unsigned _a0 = _wpk[0], _b0 = _wpk[2];                                \
        unsigned _a1 = _wpk[1], _b1 = _wpk[3];                                \
        asm volatile("v_permlane32_swap_b32 %0, %1" : "+v"(_a0), "+v"(_b0));  \
        asm volatile("v_permlane32_swap_b32 %0, %1" : "+v"(_a1), "+v"(_b1));  \
        u32x4 _pu = {_a0, _a1, _b0, _b1};                                     \
        _pb0 = __builtin_bit_cast(bf16x8, _pu);                               \
    }                                                                         \
    {                                                                         \
        unsigned _a0 = _wpk[4], _b0 = _wpk[6];                                \
        unsigned _a1 = _wpk[5], _b1 = _wpk[7];                                \
        asm volatile("v_permlane32_swap_b32 %0, %1" : "+v"(_a0), "+v"(_b0));  \
        asm volatile("v_permlane32_swap_b32 %0, %1" : "+v"(_a1), "+v"(_b1));  \
        u32x4 _pu = {_a0, _a1, _b0, _b1};                                     \
        _pb1 = __builtin_bit_cast(bf16x8, _pu);                               \
    }                                                                         \
    _Pragma("unroll")                                                         \
    for (int j = 0; j < 4; ++j)                                               \
        va[j] = *(const bf16x8*)((vbase) + j * 512 + vloff);                  \
    _Pragma("unroll")                                                         \
    for (int j = 0; j < 4; ++j)                                               \
        vb[j] = *(const bf16x8*)((vbase) + (4 + j) * 512 + vloff);            \
    __builtin_amdgcn_s_setprio(1);                                            \
    _Pragma("unroll")                                                         \
    for (int j = 0; j < 4; ++j)                                               \
        acc[j] = mfma32(va[j], _pb0, acc[j]);                                 \
    __builtin_amdgcn_s_setprio(0);                                            \
    _Pragma("unroll")                                                         \
    for (int j = 0; j < 4; ++j)                                               \
        va[j] = *(const bf16x8*)((vbase) + 4096 + j * 512 + vloff);           \
    __builtin_amdgcn_s_setprio(1);                                            \
    _Pragma("unroll")                                                         \
    for (int j = 0; j < 4; ++j)                                               \
        acc[4 + j] = mfma32(vb[j], _pb0, acc[4 + j]);                         \
    __builtin_amdgcn_s_setprio(0);                                            \
    _Pragma("unroll")                                                         \
    for (int j = 0; j < 4; ++j)                                               \
        vb[j] = *(const bf16x8*)((vbase) + 4096 + (4 + j) * 512 + vloff);     \
    __builtin_amdgcn_s_setprio(1);                                            \
    _Pragma("unroll")                                                         \
    for (int j = 0; j < 4; ++j)                                               \
        acc[j] = mfma32(va[j], _pb1, acc[j]);                                 \
    _Pragma("unroll")                                                         \
    for (int j = 0; j < 4; ++j)                                               \
        acc[4 + j] = mfma32(vb[j], _pb1, acc[4 + j]);                         \
    __builtin_amdgcn_s_setprio(0);                                            \
} while (0)

// phase = barrier + (optional) 2-strip stage + two strip bodies
#define PHASE(vcur, vnxt, STAGE, RK0, RK1) do {                               \
    __syncthreads();                                                          \
    if (STAGE) STAGEV2(vnxt);                                                 \
    STRIPBODY((vcur), RK0);                                                   \
    STRIPBODY((vcur) + 8192, RK1);                                            \
} while (0)

__global__ __launch_bounds__(256, 2) void flash14_kernel(const __bf16* __restrict__ ktile,
                                                         const float* __restrict__ qk,
                                                         const __bf16* __restrict__ vt,
                                                         const unsigned* __restrict__ ksq2,
                                                         __bf16* __restrict__ partO,
                                                         float* __restrict__ partD) {
    const int tid = threadIdx.x;
    const int w = tid >> 6, lane = tid & 63;
    const int l31 = lane & 31, h = lane >> 5;

    // XCD-chunked decomposition: 32 groups (cs2,s,b) x 18 blocks; a group's
    // 72 waves share one K/V-segment stream -> one XCD's L2.
    const int bid = blockIdx.x;            // 0..575
    const int xcd = bid & 7;
    const int ixc = bid >> 3;              // 0..71
    const int grp = ixc / 18;              // 0..3
    const int blk = ixc % 18;              // 0..17
    const int G   = xcd * 4 + grp;         // 0..31
    const int cs2 = G & 1;
    const int sb  = G >> 1;                // 0..15
    const int s   = sb & 7, b = sb >> 3;
    const int nt  = blk * 4 + w;           // 0..71

    const int n0 = nt * 32;
    const int cw = cs2 * 256;
    const int m_base = s * MSEG;

    // lane-invariant offsets (elements), computed ONCE
    const int koff  = (h * 32 + l31) * 8;
    const int vloff = lane * 8;                            // linear LDS reads
    const int cwoff = cw * 16;                             // channel window
    const int soff  = (lane & 31) * 16 + (lane >> 5) * 8;  // pre-swizzled src

    // shared V: 2 phases x 2 strips x 16KB = 64KB, fragment-ordered
    __shared__ __align__(16) __bf16 Vlds[2][16384];

    // Q' B-frags: col = n0+l31, k = 16ks+8h+i, scaled by C2Q
    const float* qkb = qk + (size_t)b * CK_ * N_;
    bf16x8 qf[4];
#pragma unroll
    for (int ks = 0; ks < 4; ++ks)
#pragma unroll
      for (int i = 0; i < 8; ++i)
        qf[ks][i] = (__bf16)(qkb[(size_t)(16*ks + 8*h + i) * N_ + (n0 + l31)] * C2Q);

    // constant B-frag: -1.0bf16 at k slots {0,1}
    const u32x4 bneg_u = {0xBF80BF80u, 0u, 0u, 0u};
    const bf16x8 bneg = __builtin_bit_cast(bf16x8, bneg_u);

    // persistent zero accumulator (C operand of the first QK MFMA)
    f32x16 fzero;
#pragma unroll
    for (int r = 0; r < 16; ++r) fzero[r] = 0.f;

    // wave-uniform stream pointers, advanced by constant strides (SALU)
    const __bf16*   kp  = ktile + (size_t)b * M_ * 64 + (size_t)m_base * 64;
    const unsigned* kqp = ksq2  + (size_t)b * M_ + m_base;
    const __bf16*   vps = vt    + (size_t)b * M_ * CV_ + (size_t)m_base * CV_;

    f32x16 acc[8];
#pragma unroll
    for (int ct = 0; ct < 8; ++ct)
#pragma unroll
      for (int r = 0; r < 16; ++r) acc[ct][r] = 0.f;
    float den[4] = {0.f, 0.f, 0.f, 0.f};

    bf16x8 kC0, kC1, kC2, kC3;
    unsigned kqC;
    bf16x8 va[4], vb[4];

    // prologue: K(0) regs + phase 0 (strips 0,1) staged into buf0
    LOADK(kC0, kC1, kC2, kC3, kqC);
    STAGEV2(&Vlds[0][0]);

    for (int it = 0; it < 17; ++it) {                 // phases 0..33 (strips 0..67)
        PHASE(&Vlds[0][0], &Vlds[1][0], 1, 1, 1);
        PHASE(&Vlds[1][0], &Vlds[0][0], 1, 1, 1);
    }
    PHASE(&Vlds[0][0], &Vlds[1][0], 1, 1, 1);         // phase 34: strips 68,69; stages 70,71
    PHASE(&Vlds[1][0], &Vlds[0][0], 0, 1, 0);         // phase 35: strips 70,71

    // denominator: lane holds sum over its 16 m-rows; add other half
    float dsum = (den[0] + den[1]) + (den[2] + den[3]);
    dsum += __shfl_xor(dsum, 32);
    if (cs2 == 0 && lane < 32)
        partD[(size_t)(s * B_ + b) * N_ + n0 + l31] = dsum;

    // unnormalized partial O in bf16: c = cw + 32ct + (r&3)+8*(r>>2)+4h
    __bf16* po = partO + (((size_t)(s * B_ + b) * CV_ + cw) * N_) + n0 + l31;
#pragma unroll
    for (int ct = 0; ct < 8; ++ct)
#pragma unroll
      for (int r = 0; r < 16; ++r) {
        const int crow = 32*ct + (r & 3) + 8*(r >> 2) + 4*h;
        po[(size_t)crow * N_] = (__bf16)acc[ct][r];
      }
}

// ---------------------------------------------------------------------------
// reduce: mem[b][c][n] = sum_s partO / sum_s partD  -> d_out channels 0..511
// ---------------------------------------------------------------------------
__global__ __launch_bounds__(256) void reduce_kernel(const __bf16* __restrict__ partO,
                                                     const float* __restrict__ partD,
                                                     float* __restrict__ out) {
    const int idx = blockIdx.x * 256 + threadIdx.x;   // B*CV*(N/8) threads
    const int n8 = idx % (N_ / 8);
    const int c  = (idx / (N_ / 8)) % CV_;
    const int b  = idx / ((N_ / 8) * CV_);
    float o[8] = {0,0,0,0,0,0,0,0};
    float dd[8] = {0,0,0,0,0,0,0,0};
#pragma unroll
    for (int s = 0; s < SSPLIT; ++s) {
        const bf16x8 ov = *(const bf16x8*)(partO + (((size_t)(s*B_+b)*CV_ + c) * N_) + n8*8);
        const float4 d0 = *(const float4*)(partD + (size_t)(s*B_+b)*N_ + n8*8);
        const float4 d1 = *(const float4*)(partD + (size_t)(s*B_+b)*N_ + n8*8 + 4);
#pragma unroll
        for (int j = 0; j < 8; ++j) o[j] += (float)ov[j];
        dd[0]+=d0.x; dd[1]+=d0.y; dd[2]+=d0.z; dd[3]+=d0.w;
        dd[4]+=d1.x; dd[5]+=d1.y; dd[6]+=d1.z; dd[7]+=d1.w;
    }
    float* op = out + ((size_t)b * (2*CV_) + c) * N_ + n8*8;
#pragma unroll
    for (int j = 0; j < 8; ++j) op[j] = o[j] / dd[j];
}

// ---------------------------------------------------------------------------
// conv_r: R_j[cc][b][p] = sum_{c in chunk cc} in[c][p] * w[c][j]
// ---------------------------------------------------------------------------
__global__ __launch_bounds__(256) void conv_r_kernel(const float* __restrict__ outf,
                                                     const float* __restrict__ qv,
                                                     const float* __restrict__ mask,
                                                     const float* __restrict__ cw,
                                                     float* __restrict__ Rp) {
    const int p  = blockIdx.x * 256 + threadIdx.x;   // 0..N-1
    const int cc = blockIdx.y;                        // 0..8
    const int b  = blockIdx.z;
    float r[9] = {0,0,0,0,0,0,0,0,0};
    if (cc < 8) {
        const float* src = (cc < 4) ? outf + ((size_t)b * (2*CV_) + cc * 128) * N_
                                    : qv   + ((size_t)b * CV_ + (cc - 4) * 128) * N_;
        const float* wb = cw + (size_t)cc * 128 * 9;
        for (int c = 0; c < 128; ++c) {
            const float v = src[(size_t)c * N_ + p];
#pragma unroll
            for (int j = 0; j < 9; ++j) r[j] += v * wb[c * 9 + j];
        }
    } else {
        const float v = mask[(size_t)b * N_ + p];
#pragma unroll
        for (int j = 0; j < 9; ++j) r[j] = v * cw[1024 * 9 + j];
    }
#pragma unroll
    for (int j = 0; j < 9; ++j)
        Rp[(((size_t)cc * 9 + j) * B_ + b) * N_ + p] = r[j];
}

// ---------------------------------------------------------------------------
// gate: gate[b][p] = sigmoid( sum_j sum_cc Rp[cc][j][b][neighbor_j(p)] + bias )
// ---------------------------------------------------------------------------
__global__ __launch_bounds__(256) void gate_kernel(const float* __restrict__ Rp,
                                                   const float* __restrict__ cbias,
                                                   float* __restrict__ gate_ws) {
    const int p = blockIdx.x * 256 + threadIdx.x;    // 0..N-1
    const int b = blockIdx.y;
    const int y = p / W_, x = p % W_;
    float sum = cbias[0];
#pragma unroll
    for (int dy = -1; dy <= 1; ++dy) {
        const int yy = y + dy;
        if (yy < 0 || yy >= H_) continue;
#pragma unroll
        for (int dx = -1; dx <= 1; ++dx) {
            const int xx = x + dx;
            if (xx < 0 || xx >= W_) continue;
            const int j = (dy + 1) * 3 + (dx + 1);
            const int q = yy * W_ + xx;
#pragma unroll
            for (int cc = 0; cc < 9; ++cc)
                sum += Rp[(((size_t)cc * 9 + j) * B_ + b) * N_ + q];
        }
    }
    gate_ws[(size_t)b * N_ + p] = 1.f / (1.f + __builtin_amdgcn_exp2f(-sum * 1.44269504f));
}

// ---------------------------------------------------------------------------
// finalize: out[b][ch][n] = (ch<512 ? mem : qv) * gate[b][n]
// ---------------------------------------------------------------------------
__global__ __launch_bounds__(256) void finalize_kernel(const float* __restrict__ qv,
                                                       const float* __restrict__ gate_ws,
                                                       float* __restrict__ out) {
    const int idx = blockIdx.x * 256 + threadIdx.x;
    const int n4 = N_ / 4;
    const int pos4 = idx % n4;
    const int row  = idx / n4;
    const int b = row >> 10, ch = row & 1023;
    const float4 gv = *(const float4*)(gate_ws + (size_t)b * N_ + pos4 * 4);
    float* op = out + (size_t)row * N_ + pos4 * 4;
    float4 v;
    if (ch < CV_) v = *(const float4*)op;
    else          v = *(const float4*)(qv + ((size_t)b * CV_ + (ch - CV_)) * N_ + pos4 * 4);
    v.x *= gv.x; v.y *= gv.y; v.z *= gv.z; v.w *= gv.w;
    *(float4*)op = v;
}

// ===========================================================================
extern "C" void kernel_launch(void* const* d_in, const int* in_sizes, int n_in,
                              void* d_out, int out_size, void* d_ws, size_t ws_size,
                              hipStream_t stream) {
    (void)in_sizes; (void)n_in; (void)out_size; (void)ws_size;
    const float* mk    = (const float*)d_in[0];
    const float* qk    = (const float*)d_in[1];
    const float* mv    = (const float*)d_in[2];
    const float* qv    = (const float*)d_in[3];
    const float* mask  = (const float*)d_in[4];
    const float* cw    = (const float*)d_in[5];
    const float* cbias = (const float*)d_in[6];
    float* outf = (float*)d_out;

    // workspace layout (bytes) — total 80,529,408, byte-identical to rounds 3-15
    const size_t kbf_b   = (size_t)B_ * M_ * 64 * 2;             //  4,718,592 (ktile; reused as Rp)
    const size_t vbf_b   = (size_t)B_ * CV_ * M_ * 2;            // 37,748,736 (vt)
    const size_t ksq_b   = (size_t)B_ * M_ * 4;                  //    147,456 (packed u32 hi/lo)
    const size_t partO_b = (size_t)SSPLIT * B_ * CV_ * N_ * 2;   // 37,748,736 (bf16)
    const size_t partD_b = (size_t)SSPLIT * B_ * N_ * 4;         //    147,456

    char* pw = (char*)d_ws;
    __bf16* ktile = (__bf16*)pw;
    float*  Rp    = (float*)pw;            // overlays ktile (dead after flash14)
    pw += kbf_b;
    __bf16* vt    = (__bf16*)pw;           pw += vbf_b;
    unsigned* ksq2 = (unsigned*)pw;        pw += ksq_b;
    __bf16* partO = (__bf16*)pw;           pw += partO_b;
    float*  partD = (float*)pw;            pw += partD_b;
    float*  gate_ws = (float*)pw;

    prep_k<<<dim3(B_ * M_ / 256), 256, 0, stream>>>(mk, ktile, ksq2);
    prep_v<<<dim3((size_t)B_ * (M_ / 16) * CV_ / 256, 1, 1), 256, 0, stream>>>(mv, vt);
    flash14_kernel<<<dim3(576), 256, 0, stream>>>(ktile, qk, vt, ksq2, partO, partD);
    reduce_kernel<<<dim3(B_ * CV_ * (N_ / 8) / 256), 256, 0, stream>>>(partO, partD, outf);
    conv_r_kernel<<<dim3(N_ / 256, 9, B_), 256, 0, stream>>>(outf, qv, mask, cw, Rp);
    gate_kernel<<<dim3(N_ / 256, B_), 256, 0, stream>>>(Rp, cbias, gate_ws);
    finalize_kernel<<<dim3((B_ * 2 * CV_ * N_ / 4) / 256), 256, 0, stream>>>(qv, gate_ws, outf);
}

// Round 17
// 198.269 us; speedup vs baseline: 1.5197x; 1.2569x over previous
//
#include <hip/hip_runtime.h>

// Problem constants (fixed by setup_inputs)
#define B_  2
#define CK_ 64
#define CV_ 512
#define H_  48
#define W_  48
#define M_  18432   // T*H*W
#define N_  2304    // H*W

#define VSTRIDE16 (CV_ * 16)   // elems per m16 block in vt = 8192

typedef __bf16 bf16x8 __attribute__((ext_vector_type(8)));
typedef float  f32x4  __attribute__((ext_vector_type(4)));
typedef float  f32x16 __attribute__((ext_vector_type(16)));
typedef unsigned int u32x4 __attribute__((ext_vector_type(4)));

// logit = (2*ab - |k|^2)/sqrt(64); exp2 domain. Q pre-scaled by C2Q,
// ksq pre-scaled by C_KSQ, stored as bf16 hi+lo pair.
#define C2Q   0.36067376f
#define C_KSQ 0.18033688f

__device__ inline f32x16 mfma32(bf16x8 a, bf16x8 b, f32x16 c) {
    return __builtin_amdgcn_mfma_f32_32x32x16_bf16(a, b, c, 0, 0, 0);
}

__device__ inline unsigned pack_bf16(float lo, float hi) {
    union { __bf16 h; unsigned short u; } a, b;
    a.h = (__bf16)lo; b.h = (__bf16)hi;
    return ((unsigned)b.u << 16) | a.u;
}

// async global->LDS, 16B per lane; LDS dest = uniform base + lane*16 (HW).
__device__ __forceinline__ void gload_lds16(const __bf16* g, __bf16* l) {
    __builtin_amdgcn_global_load_lds(
        (const __attribute__((address_space(1))) void*)g,
        (__attribute__((address_space(3))) void*)l,
        16, 0, 0);
}

// ---------------------------------------------------------------------------
// prep_k: ktile[b][mt][ks][h][l][8] : elem = K[b][m=32mt+l][k=16ks+8h+i]
// ---------------------------------------------------------------------------
__global__ __launch_bounds__(256) void prep_k(const float* __restrict__ mk,
                                              __bf16* __restrict__ ktile,
                                              unsigned* __restrict__ ksq2) {
    const int idx = blockIdx.x * 256 + threadIdx.x;   // B*M threads
    const int b = idx / M_, m = idx % M_;
    const float* src = mk + (size_t)b * CK_ * M_ + m;
    const int mt = m >> 5, l = m & 31;
    __bf16* dstb = ktile + (size_t)b * M_ * 64 + (size_t)mt * 2048 + l * 8;
    float s = 0.f;
#pragma unroll
    for (int j = 0; j < 8; ++j) {          // octet j: ks = j>>1, h = j&1
        bf16x8 o;
#pragma unroll
        for (int i = 0; i < 8; ++i) {
            float v = src[(size_t)(8 * j + i) * M_];
            s += v * v;
            o[i] = (__bf16)v;
        }
        *(bf16x8*)(dstb + (size_t)j * 256) = o;
    }
    const float tot = s * C_KSQ;
    const float hi = (float)(__bf16)tot;
    const float lo = tot - hi;
    ksq2[idx] = pack_bf16(hi, lo);
}

// ---------------------------------------------------------------------------
// prep_v: vt[b][m16][c][16] : elem = V[b][c][m=16*m16+i].
// ---------------------------------------------------------------------------
__global__ __launch_bounds__(256) void prep_v(const float* __restrict__ mv,
                                              __bf16* __restrict__ vt) {
    const int idx = blockIdx.x * 256 + threadIdx.x;   // B*1152*CV threads
    const int c   = idx % CV_;
    const int r   = idx / CV_;
    const int m16 = r % (M_ / 16);
    const int b   = r / (M_ / 16);
    const float4* s4 = (const float4*)(mv + ((size_t)b * CV_ + c) * M_ + m16 * 16);
    const float4 a0 = s4[0], a1 = s4[1], a2 = s4[2], a3 = s4[3];
    bf16x8 o0, o1;
    o0[0]=(__bf16)a0.x; o0[1]=(__bf16)a0.y; o0[2]=(__bf16)a0.z; o0[3]=(__bf16)a0.w;
    o0[4]=(__bf16)a1.x; o0[5]=(__bf16)a1.y; o0[6]=(__bf16)a1.z; o0[7]=(__bf16)a1.w;
    o1[0]=(__bf16)a2.x; o1[1]=(__bf16)a2.y; o1[2]=(__bf16)a2.z; o1[3]=(__bf16)a2.w;
    o1[4]=(__bf16)a3.x; o1[5]=(__bf16)a3.y; o1[6]=(__bf16)a3.z; o1[7]=(__bf16)a3.w;
    __bf16* dst = vt + ((size_t)r * CV_ + c) * 16;
    *(bf16x8*)dst = o0;
    *(bf16x8*)(dst + 8) = o1;
}

// ---------------------------------------------------------------------------
// flash15: flash12 inner structure (verified: LDS V double-buffer, pre-swizzled
// conflict-free staging, K reload-after-QK, permlane P redistribution) with a
// BALANCED RESIDENCY schedule: exactly 512 blocks (= 2/CU capacity, one
// dispatch round). 72 columns (ntg 18 x cs2 2 x b 2), each = full M; cols
// 0..7 get 8 blocks (72 strips each), cols 8..71 get 7 blocks (82-83 strips).
// Per-block partO slot. bid = 8*j + xcd keeps a column's blocks on one XCD.
// ---------------------------------------------------------------------------

#define LOADK() do {                                                          \
    kC0 = *(const bf16x8*)(kp + koff);                                        \
    kC1 = *(const bf16x8*)(kp + koff + 512);                                  \
    kC2 = *(const bf16x8*)(kp + koff + 1024);                                 \
    kC3 = *(const bf16x8*)(kp + koff + 1536);                                 \
    kqC = kqp[l31];                                                           \
    kp += 2048; kqp += 32;                                                    \
} while (0)

// stage one strip's V (16KB, 4 x 1KB per wave); source pre-swizzled so the
// linear LDS write order equals the fragment read order (round-14, verified).
#define STAGEV(vnxt) do {                                                     \
    _Pragma("unroll")                                                         \
    for (int i = 0; i < 4; ++i) {                                             \
        const int jj = i * 4 + w;                                             \
        const int chunk = jj >> 3, off = jj & 7;                              \
        gload_lds16(vps + chunk * VSTRIDE16 + cwoff + off * 512 + soff,       \
                    (vnxt) + chunk * 4096 + off * 512);                       \
    }                                                                         \
    vps += 2 * VSTRIDE16;                                                     \
} while (0)

__global__ __launch_bounds__(256, 2) void flash15_kernel(const __bf16* __restrict__ ktile,
                                                         const float* __restrict__ qk,
                                                         const __bf16* __restrict__ vt,
                                                         const unsigned* __restrict__ ksq2,
                                                         __bf16* __restrict__ partO,
                                                         float* __restrict__ partD) {
    const int tid = threadIdx.x;
    const int w = tid >> 6, lane = tid & 63;
    const int l31 = lane & 31, h = lane >> 5;

    // balanced col/slot mapping (512 blocks, 72 columns, 7-8 blocks each)
    const int bid = blockIdx.x;            // 0..511
    const int x = bid & 7;                 // XCD (default round-robin)
    const int j = bid >> 3;                // 0..63
    int col, slot;
    if (j < 8) { col = x;                slot = x * 8 + j; }
    else {
        const int c_loc = (j - 8) / 7, idx7 = (j - 8) % 7;
        col = 8 + x * 8 + c_loc;
        slot = 64 + (col - 8) * 7 + idx7;
    }
    const int base = (col < 8) ? col * 8 : 64 + (col - 8) * 7;
    const int idx  = slot - base;
    const int cnt  = (col < 8) ? 8 : 7;
    const int ntg  = col % 18;             // block n-group (4 n-tiles)
    const int cb   = col / 18;             // cs2 + 2*b
    const int cs2  = cb & 1, b = cb >> 1;
    const int nt   = ntg * 4 + w;          // wave's n-tile 0..71

    // strip range within the column's full-M axis (576 strips of 32 m)
    int s0, ns;
    if (cnt == 8) { s0 = idx * 72; ns = 72; }
    else if (idx < 2) { s0 = idx * 83; ns = 83; }
    else { s0 = 166 + (idx - 2) * 82; ns = 82; }

    const int n0 = nt * 32;
    const int cw = cs2 * 256;

    // lane-invariant offsets (elements), computed ONCE
    const int koff  = (h * 32 + l31) * 8;
    const int vloff = lane * 8;                            // linear LDS reads
    const int cwoff = cw * 16;                             // channel window
    const int soff  = (lane & 31) * 16 + (lane >> 5) * 8;  // pre-swizzled src

    // shared V strip buffers (fragment-ordered), 2 x 16KB
    __shared__ __align__(16) __bf16 Vlds[2][8192];

    // Q' B-frags: col = n0+l31, k = 16ks+8h+i, scaled by C2Q
    const float* qkb = qk + (size_t)b * CK_ * N_;
    bf16x8 qf[4];
#pragma unroll
    for (int ks = 0; ks < 4; ++ks)
#pragma unroll
      for (int i = 0; i < 8; ++i)
        qf[ks][i] = (__bf16)(qkb[(size_t)(16*ks + 8*h + i) * N_ + (n0 + l31)] * C2Q);

    // constant B-frag: -1.0bf16 at k slots {0,1}
    const u32x4 bneg_u = {0xBF80BF80u, 0u, 0u, 0u};
    const bf16x8 bneg = __builtin_bit_cast(bf16x8, bneg_u);

    // wave-uniform stream pointers at the block's strip range
    const __bf16*   kp  = ktile + (size_t)b * M_ * 64 + (size_t)s0 * 2048;
    const unsigned* kqp = ksq2  + (size_t)b * M_ + s0 * 32;
    const __bf16*   vps = vt    + (size_t)b * M_ * CV_ + (size_t)s0 * 2 * VSTRIDE16;

    f32x16 acc[8];
#pragma unroll
    for (int ct = 0; ct < 8; ++ct)
#pragma unroll
      for (int r = 0; r < 16; ++r) acc[ct][r] = 0.f;
    float den[4] = {0.f, 0.f, 0.f, 0.f};

    bf16x8 kC0, kC1, kC2, kC3;
    unsigned kqC;
    bf16x8 va[4], vb[4];

    // prologue: K(s0) regs + V(s0) staged into buf0
    LOADK();
    STAGEV(&Vlds[0][0]);
    const __bf16* vc = &Vlds[0][0];
    __bf16* vn = &Vlds[1][0];

    for (int s = 0; s < ns; ++s) {
        __syncthreads();
        const int more = (s + 1 < ns);
        if (more) STAGEV(vn);
        // --- QK(strip s) ---
        u32x4 a4u = { h ? 0u : kqC, 0u, 0u, 0u };
        const bf16x8 af4 = __builtin_bit_cast(bf16x8, a4u);
        f32x16 d;
#pragma unroll
        for (int r = 0; r < 16; ++r) d[r] = 0.f;
        __builtin_amdgcn_s_setprio(1);
        d = mfma32(af4, bneg, d);
        d = mfma32(kC0, qf[0], d);
        d = mfma32(kC1, qf[1], d);
        d = mfma32(kC2, qf[2], d);
        d = mfma32(kC3, qf[3], d);
        __builtin_amdgcn_s_setprio(0);
        if (more) LOADK();                  // K(s+1), regs dead
        // --- softmax numerators + pack ---
        unsigned wpk[8];
#pragma unroll
        for (int jj = 0; jj < 8; ++jj) {
            const float pa = __builtin_amdgcn_exp2f(d[2*jj]);
            const float pc = __builtin_amdgcn_exp2f(d[2*jj+1]);
            den[jj & 3] += pa + pc;
            wpk[jj] = pack_bf16(pa, pc);
        }
        bf16x8 pb0, pb1;
        {
            unsigned a0 = wpk[0], b0 = wpk[2];
            unsigned a1 = wpk[1], b1 = wpk[3];
            asm volatile("v_permlane32_swap_b32 %0, %1" : "+v"(a0), "+v"(b0));
            asm volatile("v_permlane32_swap_b32 %0, %1" : "+v"(a1), "+v"(b1));
            u32x4 pu = {a0, a1, b0, b1};
            pb0 = __builtin_bit_cast(bf16x8, pu);
        }
        {
            unsigned a0 = wpk[4], b0 = wpk[6];
            unsigned a1 = wpk[5], b1 = wpk[7];
            asm volatile("v_permlane32_swap_b32 %0, %1" : "+v"(a0), "+v"(b0));
            asm volatile("v_permlane32_swap_b32 %0, %1" : "+v"(a1), "+v"(b1));
            u32x4 pu = {a0, a1, b0, b1};
            pb1 = __builtin_bit_cast(bf16x8, pu);
        }
        // --- PV from LDS (linear lane-ordered, conflict-free) ---
#pragma unroll
        for (int jj = 0; jj < 4; ++jj)
            va[jj] = *(const bf16x8*)(vc + jj * 512 + vloff);
#pragma unroll
        for (int jj = 0; jj < 4; ++jj)
            vb[jj] = *(const bf16x8*)(vc + (4 + jj) * 512 + vloff);
        __builtin_amdgcn_s_setprio(1);
#pragma unroll
        for (int jj = 0; jj < 4; ++jj)
            acc[jj] = mfma32(va[jj], pb0, acc[jj]);
        __builtin_amdgcn_s_setprio(0);
#pragma unroll
        for (int jj = 0; jj < 4; ++jj)
            va[jj] = *(const bf16x8*)(vc + 4096 + jj * 512 + vloff);
        __builtin_amdgcn_s_setprio(1);
#pragma unroll
        for (int jj = 0; jj < 4; ++jj)
            acc[4 + jj] = mfma32(vb[jj], pb0, acc[4 + jj]);
        __builtin_amdgcn_s_setprio(0);
#pragma unroll
        for (int jj = 0; jj < 4; ++jj)
            vb[jj] = *(const bf16x8*)(vc + 4096 + (4 + jj) * 512 + vloff);
        __builtin_amdgcn_s_setprio(1);
#pragma unroll
        for (int jj = 0; jj < 4; ++jj)
            acc[jj] = mfma32(va[jj], pb1, acc[jj]);
#pragma unroll
        for (int jj = 0; jj < 4; ++jj)
            acc[4 + jj] = mfma32(vb[jj], pb1, acc[4 + jj]);
        __builtin_amdgcn_s_setprio(0);
        // ping-pong
        __bf16* t = (__bf16*)vc; vc = vn; vn = t;
    }

    // denominator: lane holds sum over its 16 m-rows; add other half
    float dsum = (den[0] + den[1]) + (den[2] + den[3]);
    dsum += __shfl_xor(dsum, 32);
    if (cs2 == 0 && lane < 32)
        partD[(size_t)slot * 128 + w * 32 + l31] = dsum;

    // partial O (bf16) into this block's slot: [ch 256][n 128]
    __bf16* po = partO + (size_t)slot * 32768 + (w * 32 + l31);
#pragma unroll
    for (int ct = 0; ct < 8; ++ct)
#pragma unroll
      for (int r = 0; r < 16; ++r) {
        const int ch = 32*ct + (r & 3) + 8*(r >> 2) + 4*h;
        po[(size_t)ch * 128] = (__bf16)acc[ct][r];
      }
}

// ---------------------------------------------------------------------------
// reduce: mem[b][c][n] = sum_slots partO / sum_slots partD -> out ch 0..511
// ---------------------------------------------------------------------------
__global__ __launch_bounds__(256) void reduce_kernel(const __bf16* __restrict__ partO,
                                                     const float* __restrict__ partD,
                                                     float* __restrict__ out) {
    const int idx = blockIdx.x * 256 + threadIdx.x;   // B*CV*(N/8) threads
    const int n8 = idx % (N_ / 8);                    // 0..287
    const int c  = (idx / (N_ / 8)) % CV_;
    const int b  = idx / ((N_ / 8) * CV_);
    const int n  = n8 * 8;
    const int ntg = n / 128, nl = n % 128;
    const int cs2 = c >> 8, chloc = c & 255;

    const int col  = ntg + 18 * (cs2 + 2 * b);
    const int colD = ntg + 36 * b;
    const int baseO = (col  < 8) ? col  * 8 : 64 + (col  - 8) * 7;
    const int cntO  = (col  < 8) ? 8 : 7;
    const int baseD = (colD < 8) ? colD * 8 : 64 + (colD - 8) * 7;
    const int cntD  = (colD < 8) ? 8 : 7;

    float o[8] = {0,0,0,0,0,0,0,0};
    for (int i = 0; i < cntO; ++i) {
        const bf16x8 ov = *(const bf16x8*)(partO + (size_t)(baseO + i) * 32768
                                           + chloc * 128 + nl);
#pragma unroll
        for (int jj = 0; jj < 8; ++jj) o[jj] += (float)ov[jj];
    }
    float dd[8] = {0,0,0,0,0,0,0,0};
    for (int i = 0; i < cntD; ++i) {
        const float4 d0 = *(const float4*)(partD + (size_t)(baseD + i) * 128 + nl);
        const float4 d1 = *(const float4*)(partD + (size_t)(baseD + i) * 128 + nl + 4);
        dd[0]+=d0.x; dd[1]+=d0.y; dd[2]+=d0.z; dd[3]+=d0.w;
        dd[4]+=d1.x; dd[5]+=d1.y; dd[6]+=d1.z; dd[7]+=d1.w;
    }
    float* op = out + ((size_t)b * (2*CV_) + c) * N_ + n;
#pragma unroll
    for (int jj = 0; jj < 8; ++jj) op[jj] = o[jj] / dd[jj];
}

// ---------------------------------------------------------------------------
// conv_r: R_j[cc][b][p] = sum_{c in chunk cc} in[c][p] * w[c][j]
// ---------------------------------------------------------------------------
__global__ __launch_bounds__(256) void conv_r_kernel(const float* __restrict__ outf,
                                                     const float* __restrict__ qv,
                                                     const float* __restrict__ mask,
                                                     const float* __restrict__ cw,
                                                     float* __restrict__ Rp) {
    const int p  = blockIdx.x * 256 + threadIdx.x;   // 0..N-1
    const int cc = blockIdx.y;                        // 0..8
    const int b  = blockIdx.z;
    float r[9] = {0,0,0,0,0,0,0,0,0};
    if (cc < 8) {
        const float* src = (cc < 4) ? outf + ((size_t)b * (2*CV_) + cc * 128) * N_
                                    : qv   + ((size_t)b * CV_ + (cc - 4) * 128) * N_;
        const float* wb = cw + (size_t)cc * 128 * 9;
        for (int c = 0; c < 128; ++c) {
            const float v = src[(size_t)c * N_ + p];
#pragma unroll
            for (int jj = 0; jj < 9; ++jj) r[jj] += v * wb[c * 9 + jj];
        }
    } else {
        const float v = mask[(size_t)b * N_ + p];
#pragma unroll
        for (int jj = 0; jj < 9; ++jj) r[jj] = v * cw[1024 * 9 + jj];
    }
#pragma unroll
    for (int jj = 0; jj < 9; ++jj)
        Rp[(((size_t)cc * 9 + jj) * B_ + b) * N_ + p] = r[jj];
}

// ---------------------------------------------------------------------------
// gate: gate[b][p] = sigmoid( sum_j sum_cc Rp[cc][j][b][neighbor_j(p)] + bias )
// ---------------------------------------------------------------------------
__global__ __launch_bounds__(256) void gate_kernel(const float* __restrict__ Rp,
                                                   const float* __restrict__ cbias,
                                                   float* __restrict__ gate_ws) {
    const int p = blockIdx.x * 256 + threadIdx.x;    // 0..N-1
    const int b = blockIdx.y;
    const int y = p / W_, x = p % W_;
    float sum = cbias[0];
#pragma unroll
    for (int dy = -1; dy <= 1; ++dy) {
        const int yy = y + dy;
        if (yy < 0 || yy >= H_) continue;
#pragma unroll
        for (int dx = -1; dx <= 1; ++dx) {
            const int xx = x + dx;
            if (xx < 0 || xx >= W_) continue;
            const int jj = (dy + 1) * 3 + (dx + 1);
            const int q = yy * W_ + xx;
#pragma unroll
            for (int cc = 0; cc < 9; ++cc)
                sum += Rp[(((size_t)cc * 9 + jj) * B_ + b) * N_ + q];
        }
    }
    gate_ws[(size_t)b * N_ + p] = 1.f / (1.f + __builtin_amdgcn_exp2f(-sum * 1.44269504f));
}

// ---------------------------------------------------------------------------
// finalize: out[b][ch][n] = (ch<512 ? mem : qv) * gate[b][n]
// ---------------------------------------------------------------------------
__global__ __launch_bounds__(256) void finalize_kernel(const float* __restrict__ qv,
                                                       const float* __restrict__ gate_ws,
                                                       float* __restrict__ out) {
    const int idx = blockIdx.x * 256 + threadIdx.x;
    const int n4 = N_ / 4;
    const int pos4 = idx % n4;
    const int row  = idx / n4;
    const int b = row >> 10, ch = row & 1023;
    const float4 gv = *(const float4*)(gate_ws + (size_t)b * N_ + pos4 * 4);
    float* op = out + (size_t)row * N_ + pos4 * 4;
    float4 v;
    if (ch < CV_) v = *(const float4*)op;
    else          v = *(const float4*)(qv + ((size_t)b * CV_ + (ch - CV_)) * N_ + pos4 * 4);
    v.x *= gv.x; v.y *= gv.y; v.z *= gv.z; v.w *= gv.w;
    *(float4*)op = v;
}

// ===========================================================================
extern "C" void kernel_launch(void* const* d_in, const int* in_sizes, int n_in,
                              void* d_out, int out_size, void* d_ws, size_t ws_size,
                              hipStream_t stream) {
    (void)in_sizes; (void)n_in; (void)out_size; (void)ws_size;
    const float* mk    = (const float*)d_in[0];
    const float* qk    = (const float*)d_in[1];
    const float* mv    = (const float*)d_in[2];
    const float* qv    = (const float*)d_in[3];
    const float* mask  = (const float*)d_in[4];
    const float* cw    = (const float*)d_in[5];
    const float* cbias = (const float*)d_in[6];
    float* outf = (float*)d_out;

    // workspace (bytes) — total 76,449,792 < proven 80,529,408 footprint
    const size_t kbf_b   = (size_t)B_ * M_ * 64 * 2;          //  4,718,592 (ktile; reused as Rp)
    const size_t vbf_b   = (size_t)B_ * CV_ * M_ * 2;         // 37,748,736 (vt)
    const size_t ksq_b   = (size_t)B_ * M_ * 4;               //    147,456
    const size_t partO_b = (size_t)512 * 32768 * 2;           // 33,554,432 (bf16, slot-indexed)
    const size_t partD_b = (size_t)512 * 128 * 4;             //    262,144

    char* pw = (char*)d_ws;
    __bf16* ktile = (__bf16*)pw;
    float*  Rp    = (float*)pw;            // overlays ktile (dead after flash15)
    pw += kbf_b;
    __bf16* vt    = (__bf16*)pw;           pw += vbf_b;
    unsigned* ksq2 = (unsigned*)pw;        pw += ksq_b;
    __bf16* partO = (__bf16*)pw;           pw += partO_b;
    float*  partD = (float*)pw;            pw += partD_b;
    float*  gate_ws = (float*)pw;

    prep_k<<<dim3(B_ * M_ / 256), 256, 0, stream>>>(mk, ktile, ksq2);
    prep_v<<<dim3((size_t)B_ * (M_ / 16) * CV_ / 256, 1, 1), 256, 0, stream>>>(mv, vt);
    flash15_kernel<<<dim3(512), 256, 0, stream>>>(ktile, qk, vt, ksq2, partO, partD);
    reduce_kernel<<<dim3(B_ * CV_ * (N_ / 8) / 256), 256, 0, stream>>>(partO, partD, outf);
    conv_r_kernel<<<dim3(N_ / 256, 9, B_), 256, 0, stream>>>(outf, qv, mask, cw, Rp);
    gate_kernel<<<dim3(N_ / 256, B_), 256, 0, stream>>>(Rp, cbias, gate_ws);
    finalize_kernel<<<dim3((B_ * 2 * CV_ * N_ / 4) / 256), 256, 0, stream>>>(qv, gate_ws, outf);
}

// Round 18
// 197.625 us; speedup vs baseline: 1.5247x; 1.0033x over previous
//
#include <hip/hip_runtime.h>

// Problem constants (fixed by setup_inputs)
#define B_  2
#define CK_ 64
#define CV_ 512
#define H_  48
#define W_  48
#define M_  18432   // T*H*W
#define N_  2304    // H*W

#define VSTRIDE16 (CV_ * 16)   // elems per m16 block in vt = 8192
#define KPBLKS    (B_ * M_ / 256)            // 144 prep_k blocks

typedef __bf16 bf16x8 __attribute__((ext_vector_type(8)));
typedef float  f32x4  __attribute__((ext_vector_type(4)));
typedef float  f32x16 __attribute__((ext_vector_type(16)));
typedef unsigned int u32x4 __attribute__((ext_vector_type(4)));

// logit = (2*ab - |k|^2)/sqrt(64); exp2 domain. Q pre-scaled by C2Q,
// ksq pre-scaled by C_KSQ, stored as bf16 hi+lo pair.
#define C2Q   0.36067376f
#define C_KSQ 0.18033688f

__device__ inline f32x16 mfma32(bf16x8 a, bf16x8 b, f32x16 c) {
    return __builtin_amdgcn_mfma_f32_32x32x16_bf16(a, b, c, 0, 0, 0);
}

__device__ inline unsigned pack_bf16(float lo, float hi) {
    union { __bf16 h; unsigned short u; } a, b;
    a.h = (__bf16)lo; b.h = (__bf16)hi;
    return ((unsigned)b.u << 16) | a.u;
}

// async global->LDS, 16B per lane; LDS dest = uniform base + lane*16 (HW).
__device__ __forceinline__ void gload_lds16(const __bf16* g, __bf16* l) {
    __builtin_amdgcn_global_load_lds(
        (const __attribute__((address_space(1))) void*)g,
        (__attribute__((address_space(3))) void*)l,
        16, 0, 0);
}

// ---------------------------------------------------------------------------
// prep_kv: fused prep. Blocks [0, KPBLKS) build ktile+ksq2; the rest build vt.
//   ktile[b][mt][ks][h][l][8] : elem = K[b][m=32mt+l][k=16ks+8h+i]
//   vt[b][m16][c][16]         : elem = V[b][c][m=16*m16+i]
// ---------------------------------------------------------------------------
__global__ __launch_bounds__(256) void prep_kv(const float* __restrict__ mk,
                                               const float* __restrict__ mv,
                                               __bf16* __restrict__ ktile,
                                               unsigned* __restrict__ ksq2,
                                               __bf16* __restrict__ vt) {
    if (blockIdx.x < KPBLKS) {
        const int idx = blockIdx.x * 256 + threadIdx.x;   // B*M threads
        const int b = idx / M_, m = idx % M_;
        const float* src = mk + (size_t)b * CK_ * M_ + m;
        const int mt = m >> 5, l = m & 31;
        __bf16* dstb = ktile + (size_t)b * M_ * 64 + (size_t)mt * 2048 + l * 8;
        float s = 0.f;
#pragma unroll
        for (int j = 0; j < 8; ++j) {          // octet j: ks = j>>1, h = j&1
            bf16x8 o;
#pragma unroll
            for (int i = 0; i < 8; ++i) {
                float v = src[(size_t)(8 * j + i) * M_];
                s += v * v;
                o[i] = (__bf16)v;
            }
            *(bf16x8*)(dstb + (size_t)j * 256) = o;
        }
        const float tot = s * C_KSQ;
        const float hi = (float)(__bf16)tot;
        const float lo = tot - hi;
        ksq2[idx] = pack_bf16(hi, lo);
    } else {
        const int idx = (blockIdx.x - KPBLKS) * 256 + threadIdx.x;
        const int c   = idx % CV_;
        const int r   = idx / CV_;
        const int m16 = r % (M_ / 16);
        const int b   = r / (M_ / 16);
        const float4* s4 = (const float4*)(mv + ((size_t)b * CV_ + c) * M_ + m16 * 16);
        const float4 a0 = s4[0], a1 = s4[1], a2 = s4[2], a3 = s4[3];
        bf16x8 o0, o1;
        o0[0]=(__bf16)a0.x; o0[1]=(__bf16)a0.y; o0[2]=(__bf16)a0.z; o0[3]=(__bf16)a0.w;
        o0[4]=(__bf16)a1.x; o0[5]=(__bf16)a1.y; o0[6]=(__bf16)a1.z; o0[7]=(__bf16)a1.w;
        o1[0]=(__bf16)a2.x; o1[1]=(__bf16)a2.y; o1[2]=(__bf16)a2.z; o1[3]=(__bf16)a2.w;
        o1[4]=(__bf16)a3.x; o1[5]=(__bf16)a3.y; o1[6]=(__bf16)a3.z; o1[7]=(__bf16)a3.w;
        __bf16* dst = vt + ((size_t)r * CV_ + c) * 16;
        *(bf16x8*)dst = o0;
        *(bf16x8*)(dst + 8) = o1;
    }
}

// ---------------------------------------------------------------------------
// flash16: round-17 flash15 (balanced 512-block residency, verified) + PV-lag
// pipeline: per strip, PV(s-1) runs between QK(s) and exp/pack(s), filling
// the QK dependency latency with 16 independent MFMAs. Packed P (8 regs)
// carried across strips; V triple-buffered in LDS (PV reads s-1 while
// stage writes s+1). vb[] dropped (JIT va batches) to pay the P-carry regs.
// Math/staging swizzle/fragment layouts identical (absmax 0.0156 lineage).
// ---------------------------------------------------------------------------

#define LOADK() do {                                                          \
    kC0 = *(const bf16x8*)(kp + koff);                                        \
    kC1 = *(const bf16x8*)(kp + koff + 512);                                  \
    kC2 = *(const bf16x8*)(kp + koff + 1024);                                 \
    kC3 = *(const bf16x8*)(kp + koff + 1536);                                 \
    kqC = kqp[l31];                                                           \
    kp += 2048; kqp += 32;                                                    \
} while (0)

// stage one strip's V (16KB, 4 x 1KB per wave); source pre-swizzled so the
// linear LDS write order equals the fragment read order (round-14, verified).
#define STAGEV(vnxt) do {                                                     \
    _Pragma("unroll")                                                         \
    for (int i = 0; i < 4; ++i) {                                             \
        const int jj = i * 4 + w;                                             \
        const int chunk = jj >> 3, off = jj & 7;                              \
        gload_lds16(vps + chunk * VSTRIDE16 + cwoff + off * 512 + soff,       \
                    (vnxt) + chunk * 4096 + off * 512);                       \
    }                                                                         \
    vps += 2 * VSTRIDE16;                                                     \
} while (0)

// QK for the strip whose K sits in kC -> d (exp2-arg, ksq folded via rank-2)
#define QKC() do {                                                            \
    u32x4 a4u = { h ? 0u : kqC, 0u, 0u, 0u };                                 \
    const bf16x8 af4 = __builtin_bit_cast(bf16x8, a4u);                       \
    _Pragma("unroll") for (int r = 0; r < 16; ++r) d[r] = 0.f;                \
    __builtin_amdgcn_s_setprio(1);                                            \
    d = mfma32(af4, bneg, d);                                                 \
    d = mfma32(kC0, qf[0], d);                                                \
    d = mfma32(kC1, qf[1], d);                                                \
    d = mfma32(kC2, qf[2], d);                                                \
    d = mfma32(kC3, qf[3], d);                                                \
    __builtin_amdgcn_s_setprio(0);                                            \
} while (0)

#define EXPPACK(P0, P1) do {                                                  \
    unsigned wpk[8];                                                          \
    _Pragma("unroll")                                                         \
    for (int jj = 0; jj < 8; ++jj) {                                          \
        const float pa = __builtin_amdgcn_exp2f(d[2*jj]);                     \
        const float pc = __builtin_amdgcn_exp2f(d[2*jj+1]);                   \
        den[jj & 3] += pa + pc;                                               \
        wpk[jj] = pack_bf16(pa, pc);                                          \
    }                                                                         \
    {                                                                         \
        unsigned a0 = wpk[0], b0 = wpk[2], a1 = wpk[1], b1 = wpk[3];          \
        asm volatile("v_permlane32_swap_b32 %0, %1" : "+v"(a0), "+v"(b0));    \
        asm volatile("v_permlane32_swap_b32 %0, %1" : "+v"(a1), "+v"(b1));    \
        u32x4 pu = {a0, a1, b0, b1};                                          \
        P0 = __builtin_bit_cast(bf16x8, pu);                                  \
    }                                                                         \
    {                                                                         \
        unsigned a0 = wpk[4], b0 = wpk[6], a1 = wpk[5], b1 = wpk[7];          \
        asm volatile("v_permlane32_swap_b32 %0, %1" : "+v"(a0), "+v"(b0));    \
        asm volatile("v_permlane32_swap_b32 %0, %1" : "+v"(a1), "+v"(b1));    \
        u32x4 pu = {a0, a1, b0, b1};                                          \
        P1 = __builtin_bit_cast(bf16x8, pu);                                  \
    }                                                                         \
} while (0)

// one PV quarter: 4 JIT va loads + 4 MFMA
#define PVQ(vbase, off, P, a0i) do {                                          \
    _Pragma("unroll")                                                         \
    for (int jj = 0; jj < 4; ++jj)                                            \
        va[jj] = *(const bf16x8*)((vbase) + (off) + jj * 512 + vloff);        \
    __builtin_amdgcn_s_setprio(1);                                            \
    _Pragma("unroll")                                                         \
    for (int jj = 0; jj < 4; ++jj)                                            \
        acc[(a0i) + jj] = mfma32(va[jj], P, acc[(a0i) + jj]);                 \
    __builtin_amdgcn_s_setprio(0);                                            \
} while (0)

#define PVBLOCK(vbase) do {                                                   \
    PVQ((vbase), 0,    pbP0, 0);                                              \
    PVQ((vbase), 2048, pbP0, 4);                                              \
    PVQ((vbase), 4096, pbP1, 0);                                              \
    PVQ((vbase), 6144, pbP1, 4);                                              \
} while (0)

__global__ __launch_bounds__(256, 2) void flash16_kernel(const __bf16* __restrict__ ktile,
                                                         const float* __restrict__ qk,
                                                         const __bf16* __restrict__ vt,
                                                         const unsigned* __restrict__ ksq2,
                                                         __bf16* __restrict__ partO,
                                                         float* __restrict__ partD) {
    const int tid = threadIdx.x;
    const int w = tid >> 6, lane = tid & 63;
    const int l31 = lane & 31, h = lane >> 5;

    // balanced col/slot mapping (512 blocks, 72 columns, 7-8 blocks each)
    const int bid = blockIdx.x;            // 0..511
    const int x = bid & 7;                 // XCD (default round-robin)
    const int j = bid >> 3;                // 0..63
    int col, slot;
    if (j < 8) { col = x;                slot = x * 8 + j; }
    else {
        const int c_loc = (j - 8) / 7, idx7 = (j - 8) % 7;
        col = 8 + x * 8 + c_loc;
        slot = 64 + (col - 8) * 7 + idx7;
    }
    const int base = (col < 8) ? col * 8 : 64 + (col - 8) * 7;
    const int idx  = slot - base;
    const int cnt  = (col < 8) ? 8 : 7;
    const int ntg  = col % 18;             // block n-group (4 n-tiles)
    const int cb   = col / 18;             // cs2 + 2*b
    const int cs2  = cb & 1, b = cb >> 1;
    const int nt   = ntg * 4 + w;          // wave's n-tile 0..71

    // strip range within the column's full-M axis (576 strips of 32 m)
    int s0, ns;
    if (cnt == 8) { s0 = idx * 72; ns = 72; }
    else if (idx < 2) { s0 = idx * 83; ns = 83; }
    else { s0 = 166 + (idx - 2) * 82; ns = 82; }

    const int n0 = nt * 32;
    const int cw = cs2 * 256;

    // lane-invariant offsets (elements), computed ONCE
    const int koff  = (h * 32 + l31) * 8;
    const int vloff = lane * 8;                            // linear LDS reads
    const int cwoff = cw * 16;                             // channel window
    const int soff  = (lane & 31) * 16 + (lane >> 5) * 8;  // pre-swizzled src

    // shared V strip buffers (fragment-ordered), 3 x 16KB (triple buffer)
    __shared__ __align__(16) __bf16 Vlds[3][8192];

    // Q' B-frags: col = n0+l31, k = 16ks+8h+i, scaled by C2Q
    const float* qkb = qk + (size_t)b * CK_ * N_;
    bf16x8 qf[4];
#pragma unroll
    for (int ks = 0; ks < 4; ++ks)
#pragma unroll
      for (int i = 0; i < 8; ++i)
        qf[ks][i] = (__bf16)(qkb[(size_t)(16*ks + 8*h + i) * N_ + (n0 + l31)] * C2Q);

    // constant B-frag: -1.0bf16 at k slots {0,1}
    const u32x4 bneg_u = {0xBF80BF80u, 0u, 0u, 0u};
    const bf16x8 bneg = __builtin_bit_cast(bf16x8, bneg_u);

    // wave-uniform stream pointers at the block's strip range
    const __bf16*   kp  = ktile + (size_t)b * M_ * 64 + (size_t)s0 * 2048;
    const unsigned* kqp = ksq2  + (size_t)b * M_ + s0 * 32;
    const __bf16*   vps = vt    + (size_t)b * M_ * CV_ + (size_t)s0 * 2 * VSTRIDE16;

    f32x16 acc[8];
#pragma unroll
    for (int ct = 0; ct < 8; ++ct)
#pragma unroll
      for (int r = 0; r < 16; ++r) acc[ct][r] = 0.f;
    float den[4] = {0.f, 0.f, 0.f, 0.f};

    bf16x8 kC0, kC1, kC2, kC3;
    unsigned kqC;
    bf16x8 va[4];
    f32x16 d;
    bf16x8 pbP0, pbP1;

    // prologue: K(s0); V(s0)->buf0; V(s0+1)->buf1; QK(s0); K(s0+1); pack(s0)
    LOADK();
    STAGEV(&Vlds[0][0]);
    STAGEV(&Vlds[1][0]);
    QKC();
    LOADK();
    EXPPACK(pbP0, pbP1);

    const __bf16* vm1  = &Vlds[0][0];   // V(s-1)
    const __bf16* vcur = &Vlds[1][0];   // V(s)
    __bf16*       vnxt = &Vlds[2][0];   // free -> V(s+1)

    for (int s = 1; s < ns; ++s) {
        __syncthreads();
        const int more = (s + 1 < ns);
        if (more) STAGEV(vnxt);
        QKC();                              // QK(s) from kC = K(s)
        if (more) LOADK();                  // K(s+1), regs dead after QKC
        PVBLOCK(vm1);                       // PV(s-1): fills QK latency
        bf16x8 pbC0, pbC1;
        EXPPACK(pbC0, pbC1);                // exp/pack(s)
        pbP0 = pbC0; pbP1 = pbC1;
        __bf16* t = (__bf16*)vm1; vm1 = vcur; vcur = vnxt; vnxt = t;
    }
    // epilogue: PV(ns-1); buffer fenced by the last body's barrier
    PVBLOCK(vm1);

    // denominator: lane holds sum over its 16 m-rows; add other half
    float dsum = (den[0] + den[1]) + (den[2] + den[3]);
    dsum += __shfl_xor(dsum, 32);
    if (cs2 == 0 && lane < 32)
        partD[(size_t)slot * 128 + w * 32 + l31] = dsum;

    // partial O (bf16) into this block's slot: [ch 256][n 128]
    __bf16* po = partO + (size_t)slot * 32768 + (w * 32 + l31);
#pragma unroll
    for (int ct = 0; ct < 8; ++ct)
#pragma unroll
      for (int r = 0; r < 16; ++r) {
        const int ch = 32*ct + (r & 3) + 8*(r >> 2) + 4*h;
        po[(size_t)ch * 128] = (__bf16)acc[ct][r];
      }
}

// ---------------------------------------------------------------------------
// reduce: mem[b][c][n] = sum_slots partO / sum_slots partD -> out ch 0..511
// ---------------------------------------------------------------------------
__global__ __launch_bounds__(256) void reduce_kernel(const __bf16* __restrict__ partO,
                                                     const float* __restrict__ partD,
                                                     float* __restrict__ out) {
    const int idx = blockIdx.x * 256 + threadIdx.x;   // B*CV*(N/8) threads
    const int n8 = idx % (N_ / 8);                    // 0..287
    const int c  = (idx / (N_ / 8)) % CV_;
    const int b  = idx / ((N_ / 8) * CV_);
    const int n  = n8 * 8;
    const int ntg = n / 128, nl = n % 128;
    const int cs2 = c >> 8, chloc = c & 255;

    const int col  = ntg + 18 * (cs2 + 2 * b);
    const int colD = ntg + 36 * b;
    const int baseO = (col  < 8) ? col  * 8 : 64 + (col  - 8) * 7;
    const int cntO  = (col  < 8) ? 8 : 7;
    const int baseD = (colD < 8) ? colD * 8 : 64 + (colD - 8) * 7;
    const int cntD  = (colD < 8) ? 8 : 7;

    float o[8] = {0,0,0,0,0,0,0,0};
    for (int i = 0; i < cntO; ++i) {
        const bf16x8 ov = *(const bf16x8*)(partO + (size_t)(baseO + i) * 32768
                                           + chloc * 128 + nl);
#pragma unroll
        for (int jj = 0; jj < 8; ++jj) o[jj] += (float)ov[jj];
    }
    float dd[8] = {0,0,0,0,0,0,0,0};
    for (int i = 0; i < cntD; ++i) {
        const float4 d0 = *(const float4*)(partD + (size_t)(baseD + i) * 128 + nl);
        const float4 d1 = *(const float4*)(partD + (size_t)(baseD + i) * 128 + nl + 4);
        dd[0]+=d0.x; dd[1]+=d0.y; dd[2]+=d0.z; dd[3]+=d0.w;
        dd[4]+=d1.x; dd[5]+=d1.y; dd[6]+=d1.z; dd[7]+=d1.w;
    }
    float* op = out + ((size_t)b * (2*CV_) + c) * N_ + n;
#pragma unroll
    for (int jj = 0; jj < 8; ++jj) op[jj] = o[jj] / dd[jj];
}

// ---------------------------------------------------------------------------
// conv_r: R_j[cc][b][p] = sum_{c in chunk cc} in[c][p] * w[c][j]
// ---------------------------------------------------------------------------
__global__ __launch_bounds__(256) void conv_r_kernel(const float* __restrict__ outf,
                                                     const float* __restrict__ qv,
                                                     const float* __restrict__ mask,
                                                     const float* __restrict__ cw,
                                                     float* __restrict__ Rp) {
    const int p  = blockIdx.x * 256 + threadIdx.x;   // 0..N-1
    const int cc = blockIdx.y;                        // 0..8
    const int b  = blockIdx.z;
    float r[9] = {0,0,0,0,0,0,0,0,0};
    if (cc < 8) {
        const float* src = (cc < 4) ? outf + ((size_t)b * (2*CV_) + cc * 128) * N_
                                    : qv   + ((size_t)b * CV_ + (cc - 4) * 128) * N_;
        const float* wb = cw + (size_t)cc * 128 * 9;
        for (int c = 0; c < 128; ++c) {
            const float v = src[(size_t)c * N_ + p];
#pragma unroll
            for (int jj = 0; jj < 9; ++jj) r[jj] += v * wb[c * 9 + jj];
        }
    } else {
        const float v = mask[(size_t)b * N_ + p];
#pragma unroll
        for (int jj = 0; jj < 9; ++jj) r[jj] = v * cw[1024 * 9 + jj];
    }
#pragma unroll
    for (int jj = 0; jj < 9; ++jj)
        Rp[(((size_t)cc * 9 + jj) * B_ + b) * N_ + p] = r[jj];
}

// ---------------------------------------------------------------------------
// gate: gate[b][p] = sigmoid( sum_j sum_cc Rp[cc][j][b][neighbor_j(p)] + bias )
// ---------------------------------------------------------------------------
__global__ __launch_bounds__(256) void gate_kernel(const float* __restrict__ Rp,
                                                   const float* __restrict__ cbias,
                                                   float* __restrict__ gate_ws) {
    const int p = blockIdx.x * 256 + threadIdx.x;    // 0..N-1
    const int b = blockIdx.y;
    const int y = p / W_, x = p % W_;
    float sum = cbias[0];
#pragma unroll
    for (int dy = -1; dy <= 1; ++dy) {
        const int yy = y + dy;
        if (yy < 0 || yy >= H_) continue;
#pragma unroll
        for (int dx = -1; dx <= 1; ++dx) {
            const int xx = x + dx;
            if (xx < 0 || xx >= W_) continue;
            const int jj = (dy + 1) * 3 + (dx + 1);
            const int q = yy * W_ + xx;
#pragma unroll
            for (int cc = 0; cc < 9; ++cc)
                sum += Rp[(((size_t)cc * 9 + jj) * B_ + b) * N_ + q];
        }
    }
    gate_ws[(size_t)b * N_ + p] = 1.f / (1.f + __builtin_amdgcn_exp2f(-sum * 1.44269504f));
}

// ---------------------------------------------------------------------------
// finalize: out[b][ch][n] = (ch<512 ? mem : qv) * gate[b][n]
// ---------------------------------------------------------------------------
__global__ __launch_bounds__(256) void finalize_kernel(const float* __restrict__ qv,
                                                       const float* __restrict__ gate_ws,
                                                       float* __restrict__ out) {
    const int idx = blockIdx.x * 256 + threadIdx.x;
    const int n4 = N_ / 4;
    const int pos4 = idx % n4;
    const int row  = idx / n4;
    const int b = row >> 10, ch = row & 1023;
    const float4 gv = *(const float4*)(gate_ws + (size_t)b * N_ + pos4 * 4);
    float* op = out + (size_t)row * N_ + pos4 * 4;
    float4 v;
    if (ch < CV_) v = *(const float4*)op;
    else          v = *(const float4*)(qv + ((size_t)b * CV_ + (ch - CV_)) * N_ + pos4 * 4);
    v.x *= gv.x; v.y *= gv.y; v.z *= gv.z; v.w *= gv.w;
    *(float4*)op = v;
}

// ===========================================================================
extern "C" void kernel_launch(void* const* d_in, const int* in_sizes, int n_in,
                              void* d_out, int out_size, void* d_ws, size_t ws_size,
                              hipStream_t stream) {
    (void)in_sizes; (void)n_in; (void)out_size; (void)ws_size;
    const float* mk    = (const float*)d_in[0];
    const float* qk    = (const float*)d_in[1];
    const float* mv    = (const float*)d_in[2];
    const float* qv    = (const float*)d_in[3];
    const float* mask  = (const float*)d_in[4];
    const float* cw    = (const float*)d_in[5];
    const float* cbias = (const float*)d_in[6];
    float* outf = (float*)d_out;

    // workspace (bytes) — total 76,449,792 (same as round 17)
    const size_t kbf_b   = (size_t)B_ * M_ * 64 * 2;          //  4,718,592 (ktile; reused as Rp)
    const size_t vbf_b   = (size_t)B_ * CV_ * M_ * 2;         // 37,748,736 (vt)
    const size_t ksq_b   = (size_t)B_ * M_ * 4;               //    147,456
    const size_t partO_b = (size_t)512 * 32768 * 2;           // 33,554,432 (bf16, slot-indexed)
    const size_t partD_b = (size_t)512 * 128 * 4;             //    262,144

    char* pw = (char*)d_ws;
    __bf16* ktile = (__bf16*)pw;
    float*  Rp    = (float*)pw;            // overlays ktile (dead after flash16)
    pw += kbf_b;
    __bf16* vt    = (__bf16*)pw;           pw += vbf_b;
    unsigned* ksq2 = (unsigned*)pw;        pw += ksq_b;
    __bf16* partO = (__bf16*)pw;           pw += partO_b;
    float*  partD = (float*)pw;            pw += partD_b;
    float*  gate_ws = (float*)pw;

    const int vblocks = (int)((size_t)B_ * (M_ / 16) * CV_ / 256);   // 9216
    prep_kv<<<dim3(KPBLKS + vblocks), 256, 0, stream>>>(mk, mv, ktile, ksq2, vt);
    flash16_kernel<<<dim3(512), 256, 0, stream>>>(ktile, qk, vt, ksq2, partO, partD);
    reduce_kernel<<<dim3(B_ * CV_ * (N_ / 8) / 256), 256, 0, stream>>>(partO, partD, outf);
    conv_r_kernel<<<dim3(N_ / 256, 9, B_), 256, 0, stream>>>(outf, qv, mask, cw, Rp);
    gate_kernel<<<dim3(N_ / 256, B_), 256, 0, stream>>>(Rp, cbias, gate_ws);
    finalize_kernel<<<dim3((B_ * 2 * CV_ * N_ / 4) / 256), 256, 0, stream>>>(qv, gate_ws, outf);
}

// Round 19
// 192.992 us; speedup vs baseline: 1.5613x; 1.0240x over previous
//
#include <hip/hip_runtime.h>

// Problem constants (fixed by setup_inputs)
#define B_  2
#define CK_ 64
#define CV_ 512
#define H_  48
#define W_  48
#define M_  18432   // T*H*W
#define N_  2304    // H*W

#define VSTRIDE16 (CV_ * 16)   // elems per m16 block in vt = 8192
#define KPBLKS    (B_ * M_ / 256)            // 144 prep_k blocks

typedef __bf16 bf16x8 __attribute__((ext_vector_type(8)));
typedef float  f32x4  __attribute__((ext_vector_type(4)));
typedef float  f32x16 __attribute__((ext_vector_type(16)));
typedef unsigned int u32x4 __attribute__((ext_vector_type(4)));

// logit = (2*ab - |k|^2)/sqrt(64); exp2 domain. Q pre-scaled by C2Q,
// ksq pre-scaled by C_KSQ, stored as bf16 hi+lo pair.
#define C2Q   0.36067376f
#define C_KSQ 0.18033688f

__device__ inline f32x16 mfma32(bf16x8 a, bf16x8 b, f32x16 c) {
    return __builtin_amdgcn_mfma_f32_32x32x16_bf16(a, b, c, 0, 0, 0);
}

__device__ inline unsigned pack_bf16(float lo, float hi) {
    union { __bf16 h; unsigned short u; } a, b;
    a.h = (__bf16)lo; b.h = (__bf16)hi;
    return ((unsigned)b.u << 16) | a.u;
}

// async global->LDS, 16B per lane; LDS dest = uniform base + lane*16 (HW).
__device__ __forceinline__ void gload_lds16(const __bf16* g, __bf16* l) {
    __builtin_amdgcn_global_load_lds(
        (const __attribute__((address_space(1))) void*)g,
        (__attribute__((address_space(3))) void*)l,
        16, 0, 0);
}

// ---------------------------------------------------------------------------
// prep_kv: fused prep (round-18, verified). Blocks [0, KPBLKS) build
// ktile+ksq2; the rest build vt.
//   ktile[b][mt][ks][h][l][8] : elem = K[b][m=32mt+l][k=16ks+8h+i]
//   vt[b][m16][c][16]         : elem = V[b][c][m=16*m16+i]
// ---------------------------------------------------------------------------
__global__ __launch_bounds__(256) void prep_kv(const float* __restrict__ mk,
                                               const float* __restrict__ mv,
                                               __bf16* __restrict__ ktile,
                                               unsigned* __restrict__ ksq2,
                                               __bf16* __restrict__ vt) {
    if (blockIdx.x < KPBLKS) {
        const int idx = blockIdx.x * 256 + threadIdx.x;   // B*M threads
        const int b = idx / M_, m = idx % M_;
        const float* src = mk + (size_t)b * CK_ * M_ + m;
        const int mt = m >> 5, l = m & 31;
        __bf16* dstb = ktile + (size_t)b * M_ * 64 + (size_t)mt * 2048 + l * 8;
        float s = 0.f;
#pragma unroll
        for (int j = 0; j < 8; ++j) {          // octet j: ks = j>>1, h = j&1
            bf16x8 o;
#pragma unroll
            for (int i = 0; i < 8; ++i) {
                float v = src[(size_t)(8 * j + i) * M_];
                s += v * v;
                o[i] = (__bf16)v;
            }
            *(bf16x8*)(dstb + (size_t)j * 256) = o;
        }
        const float tot = s * C_KSQ;
        const float hi = (float)(__bf16)tot;
        const float lo = tot - hi;
        ksq2[idx] = pack_bf16(hi, lo);
    } else {
        const int idx = (blockIdx.x - KPBLKS) * 256 + threadIdx.x;
        const int c   = idx % CV_;
        const int r   = idx / CV_;
        const int m16 = r % (M_ / 16);
        const int b   = r / (M_ / 16);
        const float4* s4 = (const float4*)(mv + ((size_t)b * CV_ + c) * M_ + m16 * 16);
        const float4 a0 = s4[0], a1 = s4[1], a2 = s4[2], a3 = s4[3];
        bf16x8 o0, o1;
        o0[0]=(__bf16)a0.x; o0[1]=(__bf16)a0.y; o0[2]=(__bf16)a0.z; o0[3]=(__bf16)a0.w;
        o0[4]=(__bf16)a1.x; o0[5]=(__bf16)a1.y; o0[6]=(__bf16)a1.z; o0[7]=(__bf16)a1.w;
        o1[0]=(__bf16)a2.x; o1[1]=(__bf16)a2.y; o1[2]=(__bf16)a2.z; o1[3]=(__bf16)a2.w;
        o1[4]=(__bf16)a3.x; o1[5]=(__bf16)a3.y; o1[6]=(__bf16)a3.z; o1[7]=(__bf16)a3.w;
        __bf16* dst = vt + ((size_t)r * CV_ + c) * 16;
        *(bf16x8*)dst = o0;
        *(bf16x8*)(dst + 8) = o1;
    }
}

// ---------------------------------------------------------------------------
// flash15: verified round-17 structure (124.5us). Balanced 512-block
// residency (one dispatch round, 2 blocks/CU), LDS V double-buffer with
// pre-swizzled conflict-free staging, K reload-after-QK one strip ahead,
// permlane P redistribution, per-strip exp/pack.
// ---------------------------------------------------------------------------

#define LOADK() do {                                                          \
    kC0 = *(const bf16x8*)(kp + koff);                                        \
    kC1 = *(const bf16x8*)(kp + koff + 512);                                  \
    kC2 = *(const bf16x8*)(kp + koff + 1024);                                 \
    kC3 = *(const bf16x8*)(kp + koff + 1536);                                 \
    kqC = kqp[l31];                                                           \
    kp += 2048; kqp += 32;                                                    \
} while (0)

// stage one strip's V (16KB, 4 x 1KB per wave); source pre-swizzled so the
// linear LDS write order equals the fragment read order (round-14, verified).
#define STAGEV(vnxt) do {                                                     \
    _Pragma("unroll")                                                         \
    for (int i = 0; i < 4; ++i) {                                             \
        const int jj = i * 4 + w;                                             \
        const int chunk = jj >> 3, off = jj & 7;                              \
        gload_lds16(vps + chunk * VSTRIDE16 + cwoff + off * 512 + soff,       \
                    (vnxt) + chunk * 4096 + off * 512);                       \
    }                                                                         \
    vps += 2 * VSTRIDE16;                                                     \
} while (0)

__global__ __launch_bounds__(256, 2) void flash15_kernel(const __bf16* __restrict__ ktile,
                                                         const float* __restrict__ qk,
                                                         const __bf16* __restrict__ vt,
                                                         const unsigned* __restrict__ ksq2,
                                                         __bf16* __restrict__ partO,
                                                         float* __restrict__ partD) {
    const int tid = threadIdx.x;
    const int w = tid >> 6, lane = tid & 63;
    const int l31 = lane & 31, h = lane >> 5;

    // balanced col/slot mapping (512 blocks, 72 columns, 7-8 blocks each)
    const int bid = blockIdx.x;            // 0..511
    const int x = bid & 7;                 // XCD (default round-robin)
    const int j = bid >> 3;                // 0..63
    int col, slot;
    if (j < 8) { col = x;                slot = x * 8 + j; }
    else {
        const int c_loc = (j - 8) / 7, idx7 = (j - 8) % 7;
        col = 8 + x * 8 + c_loc;
        slot = 64 + (col - 8) * 7 + idx7;
    }
    const int base = (col < 8) ? col * 8 : 64 + (col - 8) * 7;
    const int idx  = slot - base;
    const int cnt  = (col < 8) ? 8 : 7;
    const int ntg  = col % 18;             // block n-group (4 n-tiles)
    const int cb   = col / 18;             // cs2 + 2*b
    const int cs2  = cb & 1, b = cb >> 1;
    const int nt   = ntg * 4 + w;          // wave's n-tile 0..71

    // strip range within the column's full-M axis (576 strips of 32 m)
    int s0, ns;
    if (cnt == 8) { s0 = idx * 72; ns = 72; }
    else if (idx < 2) { s0 = idx * 83; ns = 83; }
    else { s0 = 166 + (idx - 2) * 82; ns = 82; }

    const int n0 = nt * 32;
    const int cw = cs2 * 256;

    // lane-invariant offsets (elements), computed ONCE
    const int koff  = (h * 32 + l31) * 8;
    const int vloff = lane * 8;                            // linear LDS reads
    const int cwoff = cw * 16;                             // channel window
    const int soff  = (lane & 31) * 16 + (lane >> 5) * 8;  // pre-swizzled src

    // shared V strip buffers (fragment-ordered), 2 x 16KB
    __shared__ __align__(16) __bf16 Vlds[2][8192];

    // Q' B-frags: col = n0+l31, k = 16ks+8h+i, scaled by C2Q
    const float* qkb = qk + (size_t)b * CK_ * N_;
    bf16x8 qf[4];
#pragma unroll
    for (int ks = 0; ks < 4; ++ks)
#pragma unroll
      for (int i = 0; i < 8; ++i)
        qf[ks][i] = (__bf16)(qkb[(size_t)(16*ks + 8*h + i) * N_ + (n0 + l31)] * C2Q);

    // constant B-frag: -1.0bf16 at k slots {0,1}
    const u32x4 bneg_u = {0xBF80BF80u, 0u, 0u, 0u};
    const bf16x8 bneg = __builtin_bit_cast(bf16x8, bneg_u);

    // wave-uniform stream pointers at the block's strip range
    const __bf16*   kp  = ktile + (size_t)b * M_ * 64 + (size_t)s0 * 2048;
    const unsigned* kqp = ksq2  + (size_t)b * M_ + s0 * 32;
    const __bf16*   vps = vt    + (size_t)b * M_ * CV_ + (size_t)s0 * 2 * VSTRIDE16;

    f32x16 acc[8];
#pragma unroll
    for (int ct = 0; ct < 8; ++ct)
#pragma unroll
      for (int r = 0; r < 16; ++r) acc[ct][r] = 0.f;
    float den[4] = {0.f, 0.f, 0.f, 0.f};

    bf16x8 kC0, kC1, kC2, kC3;
    unsigned kqC;
    bf16x8 va[4], vb[4];

    // prologue: K(s0) regs + V(s0) staged into buf0
    LOADK();
    STAGEV(&Vlds[0][0]);
    const __bf16* vc = &Vlds[0][0];
    __bf16* vn = &Vlds[1][0];

    for (int s = 0; s < ns; ++s) {
        __syncthreads();
        const int more = (s + 1 < ns);
        if (more) STAGEV(vn);
        // --- QK(strip s) ---
        u32x4 a4u = { h ? 0u : kqC, 0u, 0u, 0u };
        const bf16x8 af4 = __builtin_bit_cast(bf16x8, a4u);
        f32x16 d;
#pragma unroll
        for (int r = 0; r < 16; ++r) d[r] = 0.f;
        __builtin_amdgcn_s_setprio(1);
        d = mfma32(af4, bneg, d);
        d = mfma32(kC0, qf[0], d);
        d = mfma32(kC1, qf[1], d);
        d = mfma32(kC2, qf[2], d);
        d = mfma32(kC3, qf[3], d);
        __builtin_amdgcn_s_setprio(0);
        if (more) LOADK();                  // K(s+1), regs dead
        // --- softmax numerators + pack ---
        unsigned wpk[8];
#pragma unroll
        for (int jj = 0; jj < 8; ++jj) {
            const float pa = __builtin_amdgcn_exp2f(d[2*jj]);
            const float pc = __builtin_amdgcn_exp2f(d[2*jj+1]);
            den[jj & 3] += pa + pc;
            wpk[jj] = pack_bf16(pa, pc);
        }
        bf16x8 pb0, pb1;
        {
            unsigned a0 = wpk[0], b0 = wpk[2];
            unsigned a1 = wpk[1], b1 = wpk[3];
            asm volatile("v_permlane32_swap_b32 %0, %1" : "+v"(a0), "+v"(b0));
            asm volatile("v_permlane32_swap_b32 %0, %1" : "+v"(a1), "+v"(b1));
            u32x4 pu = {a0, a1, b0, b1};
            pb0 = __builtin_bit_cast(bf16x8, pu);
        }
        {
            unsigned a0 = wpk[4], b0 = wpk[6];
            unsigned a1 = wpk[5], b1 = wpk[7];
            asm volatile("v_permlane32_swap_b32 %0, %1" : "+v"(a0), "+v"(b0));
            asm volatile("v_permlane32_swap_b32 %0, %1" : "+v"(a1), "+v"(b1));
            u32x4 pu = {a0, a1, b0, b1};
            pb1 = __builtin_bit_cast(bf16x8, pu);
        }
        // --- PV from LDS (linear lane-ordered, conflict-free) ---
#pragma unroll
        for (int jj = 0; jj < 4; ++jj)
            va[jj] = *(const bf16x8*)(vc + jj * 512 + vloff);
#pragma unroll
        for (int jj = 0; jj < 4; ++jj)
            vb[jj] = *(const bf16x8*)(vc + (4 + jj) * 512 + vloff);
        __builtin_amdgcn_s_setprio(1);
#pragma unroll
        for (int jj = 0; jj < 4; ++jj)
            acc[jj] = mfma32(va[jj], pb0, acc[jj]);
        __builtin_amdgcn_s_setprio(0);
#pragma unroll
        for (int jj = 0; jj < 4; ++jj)
            va[jj] = *(const bf16x8*)(vc + 4096 + jj * 512 + vloff);
        __builtin_amdgcn_s_setprio(1);
#pragma unroll
        for (int jj = 0; jj < 4; ++jj)
            acc[4 + jj] = mfma32(vb[jj], pb0, acc[4 + jj]);
        __builtin_amdgcn_s_setprio(0);
#pragma unroll
        for (int jj = 0; jj < 4; ++jj)
            vb[jj] = *(const bf16x8*)(vc + 4096 + (4 + jj) * 512 + vloff);
        __builtin_amdgcn_s_setprio(1);
#pragma unroll
        for (int jj = 0; jj < 4; ++jj)
            acc[jj] = mfma32(va[jj], pb1, acc[jj]);
#pragma unroll
        for (int jj = 0; jj < 4; ++jj)
            acc[4 + jj] = mfma32(vb[jj], pb1, acc[4 + jj]);
        __builtin_amdgcn_s_setprio(0);
        // ping-pong
        __bf16* t = (__bf16*)vc; vc = vn; vn = t;
    }

    // denominator: lane holds sum over its 16 m-rows; add other half
    float dsum = (den[0] + den[1]) + (den[2] + den[3]);
    dsum += __shfl_xor(dsum, 32);
    if (cs2 == 0 && lane < 32)
        partD[(size_t)slot * 128 + w * 32 + l31] = dsum;

    // partial O (bf16) into this block's slot: [ch 256][n 128]
    __bf16* po = partO + (size_t)slot * 32768 + (w * 32 + l31);
#pragma unroll
    for (int ct = 0; ct < 8; ++ct)
#pragma unroll
      for (int r = 0; r < 16; ++r) {
        const int ch = 32*ct + (r & 3) + 8*(r >> 2) + 4*h;
        po[(size_t)ch * 128] = (__bf16)acc[ct][r];
      }
}

// ---------------------------------------------------------------------------
// reduce: mem[b][c][n] = sum_slots partO / sum_slots partD -> out ch 0..511
// ---------------------------------------------------------------------------
__global__ __launch_bounds__(256) void reduce_kernel(const __bf16* __restrict__ partO,
                                                     const float* __restrict__ partD,
                                                     float* __restrict__ out) {
    const int idx = blockIdx.x * 256 + threadIdx.x;   // B*CV*(N/8) threads
    const int n8 = idx % (N_ / 8);                    // 0..287
    const int c  = (idx / (N_ / 8)) % CV_;
    const int b  = idx / ((N_ / 8) * CV_);
    const int n  = n8 * 8;
    const int ntg = n / 128, nl = n % 128;
    const int cs2 = c >> 8, chloc = c & 255;

    const int col  = ntg + 18 * (cs2 + 2 * b);
    const int colD = ntg + 36 * b;
    const int baseO = (col  < 8) ? col  * 8 : 64 + (col  - 8) * 7;
    const int cntO  = (col  < 8) ? 8 : 7;
    const int baseD = (colD < 8) ? colD * 8 : 64 + (colD - 8) * 7;
    const int cntD  = (colD < 8) ? 8 : 7;

    float o[8] = {0,0,0,0,0,0,0,0};
    for (int i = 0; i < cntO; ++i) {
        const bf16x8 ov = *(const bf16x8*)(partO + (size_t)(baseO + i) * 32768
                                           + chloc * 128 + nl);
#pragma unroll
        for (int jj = 0; jj < 8; ++jj) o[jj] += (float)ov[jj];
    }
    float dd[8] = {0,0,0,0,0,0,0,0};
    for (int i = 0; i < cntD; ++i) {
        const float4 d0 = *(const float4*)(partD + (size_t)(baseD + i) * 128 + nl);
        const float4 d1 = *(const float4*)(partD + (size_t)(baseD + i) * 128 + nl + 4);
        dd[0]+=d0.x; dd[1]+=d0.y; dd[2]+=d0.z; dd[3]+=d0.w;
        dd[4]+=d1.x; dd[5]+=d1.y; dd[6]+=d1.z; dd[7]+=d1.w;
    }
    float* op = out + ((size_t)b * (2*CV_) + c) * N_ + n;
#pragma unroll
    for (int jj = 0; jj < 8; ++jj) op[jj] = o[jj] / dd[jj];
}

// ---------------------------------------------------------------------------
// conv_r: R_j[cc][b][p] = sum_{c in chunk cc} in[c][p] * w[c][j]
// ---------------------------------------------------------------------------
__global__ __launch_bounds__(256) void conv_r_kernel(const float* __restrict__ outf,
                                                     const float* __restrict__ qv,
                                                     const float* __restrict__ mask,
                                                     const float* __restrict__ cw,
                                                     float* __restrict__ Rp) {
    const int p  = blockIdx.x * 256 + threadIdx.x;   // 0..N-1
    const int cc = blockIdx.y;                        // 0..8
    const int b  = blockIdx.z;
    float r[9] = {0,0,0,0,0,0,0,0,0};
    if (cc < 8) {
        const float* src = (cc < 4) ? outf + ((size_t)b * (2*CV_) + cc * 128) * N_
                                    : qv   + ((size_t)b * CV_ + (cc - 4) * 128) * N_;
        const float* wb = cw + (size_t)cc * 128 * 9;
        for (int c = 0; c < 128; ++c) {
            const float v = src[(size_t)c * N_ + p];
#pragma unroll
            for (int jj = 0; jj < 9; ++jj) r[jj] += v * wb[c * 9 + jj];
        }
    } else {
        const float v = mask[(size_t)b * N_ + p];
#pragma unroll
        for (int jj = 0; jj < 9; ++jj) r[jj] = v * cw[1024 * 9 + jj];
    }
#pragma unroll
    for (int jj = 0; jj < 9; ++jj)
        Rp[(((size_t)cc * 9 + jj) * B_ + b) * N_ + p] = r[jj];
}

// ---------------------------------------------------------------------------
// gate: gate[b][p] = sigmoid( sum_j sum_cc Rp[cc][j][b][neighbor_j(p)] + bias )
// ---------------------------------------------------------------------------
__global__ __launch_bounds__(256) void gate_kernel(const float* __restrict__ Rp,
                                                   const float* __restrict__ cbias,
                                                   float* __restrict__ gate_ws) {
    const int p = blockIdx.x * 256 + threadIdx.x;    // 0..N-1
    const int b = blockIdx.y;
    const int y = p / W_, x = p % W_;
    float sum = cbias[0];
#pragma unroll
    for (int dy = -1; dy <= 1; ++dy) {
        const int yy = y + dy;
        if (yy < 0 || yy >= H_) continue;
#pragma unroll
        for (int dx = -1; dx <= 1; ++dx) {
            const int xx = x + dx;
            if (xx < 0 || xx >= W_) continue;
            const int jj = (dy + 1) * 3 + (dx + 1);
            const int q = yy * W_ + xx;
#pragma unroll
            for (int cc = 0; cc < 9; ++cc)
                sum += Rp[(((size_t)cc * 9 + jj) * B_ + b) * N_ + q];
        }
    }
    gate_ws[(size_t)b * N_ + p] = 1.f / (1.f + __builtin_amdgcn_exp2f(-sum * 1.44269504f));
}

// ---------------------------------------------------------------------------
// finalize: out[b][ch][n] = (ch<512 ? mem : qv) * gate[b][n]
// ---------------------------------------------------------------------------
__global__ __launch_bounds__(256) void finalize_kernel(const float* __restrict__ qv,
                                                       const float* __restrict__ gate_ws,
                                                       float* __restrict__ out) {
    const int idx = blockIdx.x * 256 + threadIdx.x;
    const int n4 = N_ / 4;
    const int pos4 = idx % n4;
    const int row  = idx / n4;
    const int b = row >> 10, ch = row & 1023;
    const float4 gv = *(const float4*)(gate_ws + (size_t)b * N_ + pos4 * 4);
    float* op = out + (size_t)row * N_ + pos4 * 4;
    float4 v;
    if (ch < CV_) v = *(const float4*)op;
    else          v = *(const float4*)(qv + ((size_t)b * CV_ + (ch - CV_)) * N_ + pos4 * 4);
    v.x *= gv.x; v.y *= gv.y; v.z *= gv.z; v.w *= gv.w;
    *(float4*)op = v;
}

// ===========================================================================
extern "C" void kernel_launch(void* const* d_in, const int* in_sizes, int n_in,
                              void* d_out, int out_size, void* d_ws, size_t ws_size,
                              hipStream_t stream) {
    (void)in_sizes; (void)n_in; (void)out_size; (void)ws_size;
    const float* mk    = (const float*)d_in[0];
    const float* qk    = (const float*)d_in[1];
    const float* mv    = (const float*)d_in[2];
    const float* qv    = (const float*)d_in[3];
    const float* mask  = (const float*)d_in[4];
    const float* cw    = (const float*)d_in[5];
    const float* cbias = (const float*)d_in[6];
    float* outf = (float*)d_out;

    // workspace (bytes) — total 76,449,792 (same as rounds 17/18)
    const size_t kbf_b   = (size_t)B_ * M_ * 64 * 2;          //  4,718,592 (ktile; reused as Rp)
    const size_t vbf_b   = (size_t)B_ * CV_ * M_ * 2;         // 37,748,736 (vt)
    const size_t ksq_b   = (size_t)B_ * M_ * 4;               //    147,456
    const size_t partO_b = (size_t)512 * 32768 * 2;           // 33,554,432 (bf16, slot-indexed)
    const size_t partD_b = (size_t)512 * 128 * 4;             //    262,144

    char* pw = (char*)d_ws;
    __bf16* ktile = (__bf16*)pw;
    float*  Rp    = (float*)pw;            // overlays ktile (dead after flash15)
    pw += kbf_b;
    __bf16* vt    = (__bf16*)pw;           pw += vbf_b;
    unsigned* ksq2 = (unsigned*)pw;        pw += ksq_b;
    __bf16* partO = (__bf16*)pw;           pw += partO_b;
    float*  partD = (float*)pw;            pw += partD_b;
    float*  gate_ws = (float*)pw;

    const int vblocks = (int)((size_t)B_ * (M_ / 16) * CV_ / 256);   // 9216
    prep_kv<<<dim3(KPBLKS + vblocks), 256, 0, stream>>>(mk, mv, ktile, ksq2, vt);
    flash15_kernel<<<dim3(512), 256, 0, stream>>>(ktile, qk, vt, ksq2, partO, partD);
    reduce_kernel<<<dim3(B_ * CV_ * (N_ / 8) / 256), 256, 0, stream>>>(partO, partD, outf);
    conv_r_kernel<<<dim3(N_ / 256, 9, B_), 256, 0, stream>>>(outf, qv, mask, cw, Rp);
    gate_kernel<<<dim3(N_ / 256, B_), 256, 0, stream>>>(Rp, cbias, gate_ws);
    finalize_kernel<<<dim3((B_ * 2 * CV_ * N_ / 4) / 256), 256, 0, stream>>>(qv, gate_ws, outf);
}